// Round 1
// baseline (9940.958 us; speedup 1.0000x reference)
//
#include <hip/hip_runtime.h>
#include <math.h>

namespace {

constexpr int B_ = 4;
constexpr int C_ = 256;
constexpr int C4_ = 64;
constexpr int N_ = 4096;

__device__ __forceinline__ float wave_sum(float v) {
#pragma unroll
    for (int k = 32; k >= 1; k >>= 1) v += __shfl_xor(v, k, 64);
    return v;
}

__device__ __forceinline__ unsigned bf16_rne(float f) {
    unsigned u = __float_as_uint(f);
    u += 0x7fffu + ((u >> 16) & 1u);
    return u >> 16;
}

// out[b,o,n] = (bias?) + sum_c W[o,c] * x[b,c,n]
template <int O, int OPT>
__global__ __launch_bounds__(256) void proj_kernel(
        const float* __restrict__ x, const float* __restrict__ W,
        const float* __restrict__ bias, float* __restrict__ out) {
    const int n = blockIdx.x * 256 + threadIdx.x;
    const int o0 = blockIdx.y * OPT;
    const int b = blockIdx.z;
    float acc[OPT];
#pragma unroll
    for (int j = 0; j < OPT; ++j) acc[j] = bias ? bias[o0 + j] : 0.0f;
    const float* xp = x + (size_t)b * C_ * N_ + n;
    const float* wp = W + (size_t)o0 * C_;
#pragma unroll 4
    for (int c = 0; c < C_; ++c) {
        const float xv = xp[(size_t)c * N_];
#pragma unroll
        for (int j = 0; j < OPT; ++j) acc[j] += wp[j * C_ + c] * xv;
    }
#pragma unroll
    for (int j = 0; j < OPT; ++j)
        out[((size_t)b * O + o0 + j) * N_ + n] = acc[j];
}

// Per-row softmax stats over e[n,m] = sum_o qk[b,o,n]*qk[b,o,m]
__global__ __launch_bounds__(256) void rowstats_kernel(
        const float* __restrict__ qk, float* __restrict__ rowmax,
        float* __restrict__ rowsum) {
    constexpr int NT = 8;
    const int b = blockIdx.y;
    const int n0 = blockIdx.x * NT;
    const int tid = threadIdx.x;
    __shared__ float qs[C4_][NT];
    __shared__ float red_m[NT][4];
    __shared__ float red_s[NT][4];
    for (int idx = tid; idx < C4_ * NT; idx += 256) {
        const int o = idx >> 3, r = idx & 7;
        qs[o][r] = qk[((size_t)b * C4_ + o) * N_ + n0 + r];
    }
    __syncthreads();
    float mx[NT], sm[NT];
#pragma unroll
    for (int r = 0; r < NT; ++r) { mx[r] = -INFINITY; sm[r] = 0.0f; }
    const float* kb = qk + (size_t)b * C4_ * N_;
    for (int i = 0; i < N_ / 256; ++i) {
        const int m = tid + i * 256;
        float e[NT] = {};
#pragma unroll 4
        for (int o = 0; o < C4_; ++o) {
            const float kv = kb[(size_t)o * N_ + m];
            const float4* q4 = reinterpret_cast<const float4*>(qs[o]);
            const float4 qa = q4[0], qb2 = q4[1];
            e[0] += qa.x * kv; e[1] += qa.y * kv;
            e[2] += qa.z * kv; e[3] += qa.w * kv;
            e[4] += qb2.x * kv; e[5] += qb2.y * kv;
            e[6] += qb2.z * kv; e[7] += qb2.w * kv;
        }
#pragma unroll
        for (int r = 0; r < NT; ++r) {
            const float nm = fmaxf(mx[r], e[r]);
            sm[r] = sm[r] * __expf(mx[r] - nm) + __expf(e[r] - nm);
            mx[r] = nm;
        }
    }
    const int wave = tid >> 6, lane = tid & 63;
#pragma unroll
    for (int r = 0; r < NT; ++r) {
#pragma unroll
        for (int k = 32; k >= 1; k >>= 1) {
            const float om = __shfl_xor(mx[r], k, 64);
            const float os = __shfl_xor(sm[r], k, 64);
            const float nm = fmaxf(mx[r], om);
            sm[r] = sm[r] * __expf(mx[r] - nm) + os * __expf(om - nm);
            mx[r] = nm;
        }
        if (lane == 0) { red_m[r][wave] = mx[r]; red_s[r][wave] = sm[r]; }
    }
    __syncthreads();
    if (tid < NT) {
        float m0 = red_m[tid][0], s0 = red_s[tid][0];
#pragma unroll
        for (int w = 1; w < 4; ++w) {
            const float m1 = red_m[tid][w], s1 = red_s[tid][w];
            const float nm = fmaxf(m0, m1);
            s0 = s0 * __expf(m0 - nm) + s1 * __expf(m1 - nm);
            m0 = nm;
        }
        rowmax[(size_t)b * N_ + n0 + tid] = m0;
        rowsum[(size_t)b * N_ + n0 + tid] = s0;
    }
}

// colsum[b,m] = sum_n exp(e[n,m]-rowmax[n]) / rowsum[n]
__global__ __launch_bounds__(256) void colstats_kernel(
        const float* __restrict__ qk, const float* __restrict__ rowmax,
        const float* __restrict__ rowsum, float* __restrict__ colsum) {
    constexpr int NT = 8;
    const int b = blockIdx.y;
    const int m0 = blockIdx.x * NT;
    const int tid = threadIdx.x;
    __shared__ float ks[C4_][NT];
    __shared__ float red[NT][4];
    for (int idx = tid; idx < C4_ * NT; idx += 256) {
        const int o = idx >> 3, r = idx & 7;
        ks[o][r] = qk[((size_t)b * C4_ + o) * N_ + m0 + r];
    }
    __syncthreads();
    float cs[NT] = {};
    const float* qb = qk + (size_t)b * C4_ * N_;
    for (int i = 0; i < N_ / 256; ++i) {
        const int n = tid + i * 256;
        float e[NT] = {};
#pragma unroll 4
        for (int o = 0; o < C4_; ++o) {
            const float qv = qb[(size_t)o * N_ + n];
            const float4* k4 = reinterpret_cast<const float4*>(ks[o]);
            const float4 ka = k4[0], kb2 = k4[1];
            e[0] += ka.x * qv; e[1] += ka.y * qv;
            e[2] += ka.z * qv; e[3] += ka.w * qv;
            e[4] += kb2.x * qv; e[5] += kb2.y * qv;
            e[6] += kb2.z * qv; e[7] += kb2.w * qv;
        }
        const float mxn = rowmax[(size_t)b * N_ + n];
        const float il = 1.0f / rowsum[(size_t)b * N_ + n];
#pragma unroll
        for (int r = 0; r < NT; ++r) cs[r] += __expf(e[r] - mxn) * il;
    }
    const int wave = tid >> 6, lane = tid & 63;
#pragma unroll
    for (int r = 0; r < NT; ++r) {
        const float s = wave_sum(cs[r]);
        if (lane == 0) red[r][wave] = s;
    }
    __syncthreads();
    if (tid < NT)
        colsum[(size_t)b * N_ + m0 + tid] =
            red[tid][0] + red[tid][1] + red[tid][2] + red[tid][3];
}

// Recompute P for a 4-row strip, contract with V, then wt-matmul + BN + ReLU + residual.
__global__ __launch_bounds__(256) void final_kernel(
        const float* __restrict__ x, const float* __restrict__ qk,
        const float* __restrict__ v, const float* __restrict__ rowmax,
        const float* __restrict__ rowsum, const float* __restrict__ colsum,
        const float* __restrict__ wt, const float* __restrict__ bt,
        const float* __restrict__ gamma, const float* __restrict__ beta,
        const float* __restrict__ rmean, const float* __restrict__ rvar,
        float* __restrict__ out) {
    constexpr int NT = 4;
    const int b = blockIdx.y;
    const int n0 = blockIdx.x * NT;
    const int tid = threadIdx.x;
    __shared__ float qs[C4_][NT];   // 1 KB
    __shared__ uint2 ps[N_];        // 32 KB: 4 bf16 p-values per m
    __shared__ float dsm[NT][C_];   // 4 KB: (x - x_r) strip
    __shared__ float wtile[16][C_]; // 16 KB
    for (int idx = tid; idx < C4_ * NT; idx += 256) {
        const int o = idx >> 2, r = idx & 3;
        qs[o][r] = qk[((size_t)b * C4_ + o) * N_ + n0 + r];
    }
    float rmx[NT], rli[NT];
#pragma unroll
    for (int r = 0; r < NT; ++r) {
        rmx[r] = rowmax[(size_t)b * N_ + n0 + r];
        rli[r] = 1.0f / rowsum[(size_t)b * N_ + n0 + r];
    }
    __syncthreads();
    // phase 1: p[r][m] = exp(e-mx)/l / (1e-9+colsum[m]), packed bf16
    const float* kb = qk + (size_t)b * C4_ * N_;
    for (int i = 0; i < N_ / 256; ++i) {
        const int m = tid + i * 256;
        float e[NT] = {};
#pragma unroll 4
        for (int o = 0; o < C4_; ++o) {
            const float kv = kb[(size_t)o * N_ + m];
            const float4 q4 = *reinterpret_cast<const float4*>(qs[o]);
            e[0] += q4.x * kv; e[1] += q4.y * kv;
            e[2] += q4.z * kv; e[3] += q4.w * kv;
        }
        const float ci = 1.0f / (1e-9f + colsum[(size_t)b * N_ + m]);
        const unsigned p0 = bf16_rne(__expf(e[0] - rmx[0]) * rli[0] * ci);
        const unsigned p1 = bf16_rne(__expf(e[1] - rmx[1]) * rli[1] * ci);
        const unsigned p2 = bf16_rne(__expf(e[2] - rmx[2]) * rli[2] * ci);
        const unsigned p3 = bf16_rne(__expf(e[3] - rmx[3]) * rli[3] * ci);
        ps[m] = make_uint2(p0 | (p1 << 16), p2 | (p3 << 16));
    }
    __syncthreads();
    // phase 2: x_r[c, n0+r] = sum_m p[r][m] * v[b,c,m]; dsm = x - x_r
    const int wave = tid >> 6, lane = tid & 63;
    for (int c = wave; c < C_; c += 4) {
        float acc[NT] = {};
        const float* vp = v + ((size_t)b * C_ + c) * N_;
        for (int m = lane; m < N_; m += 64) {
            const float vv = vp[m];
            const uint2 pk = ps[m];
            acc[0] += __uint_as_float(pk.x << 16) * vv;
            acc[1] += __uint_as_float(pk.x & 0xffff0000u) * vv;
            acc[2] += __uint_as_float(pk.y << 16) * vv;
            acc[3] += __uint_as_float(pk.y & 0xffff0000u) * vv;
        }
#pragma unroll
        for (int r = 0; r < NT; ++r) {
            const float xr = wave_sum(acc[r]);
            if (lane == 0)
                dsm[r][c] = x[((size_t)b * C_ + c) * N_ + n0 + r] - xr;
        }
    }
    __syncthreads();
    // phase 3: t[o] = bt[o] + sum_c wt[o,c]*dsm[c]; BN; ReLU; residual.
    float tacc[NT];
    const float bto = bt[tid];
#pragma unroll
    for (int r = 0; r < NT; ++r) tacc[r] = bto;
    for (int c0 = 0; c0 < C_; c0 += 16) {
        for (int idx = tid; idx < 16 * C_; idx += 256) {
            const int o = idx >> 4, cl = idx & 15;
            wtile[cl][o] = wt[(size_t)o * C_ + c0 + cl];
        }
        __syncthreads();
#pragma unroll
        for (int cl = 0; cl < 16; ++cl) {
            const float w = wtile[cl][tid];
#pragma unroll
            for (int r = 0; r < NT; ++r) tacc[r] += w * dsm[r][c0 + cl];
        }
        __syncthreads();
    }
    const float g = gamma[tid] * rsqrtf(rvar[tid] + 1e-5f);
    const float mn = rmean[tid], bb = beta[tid];
#pragma unroll
    for (int r = 0; r < NT; ++r) {
        const float bnv = (tacc[r] - mn) * g + bb;
        const size_t oi = ((size_t)b * C_ + tid) * N_ + n0 + r;
        out[oi] = x[oi] + fmaxf(bnv, 0.0f);
    }
}

}  // namespace

extern "C" void kernel_launch(void* const* d_in, const int* in_sizes, int n_in,
                              void* d_out, int out_size, void* d_ws, size_t ws_size,
                              hipStream_t stream) {
    const float* x = (const float*)d_in[0];
    const float* wq = (const float*)d_in[1];
    const float* wv = (const float*)d_in[2];
    const float* bv = (const float*)d_in[3];
    const float* wt = (const float*)d_in[4];
    const float* bt = (const float*)d_in[5];
    const float* gamma = (const float*)d_in[6];
    const float* beta = (const float*)d_in[7];
    const float* rmean = (const float*)d_in[8];
    const float* rvar = (const float*)d_in[9];
    float* out = (float*)d_out;

    // workspace layout (floats): qk[B,C4,N] | v[B,C,N] | rowmax | rowsum | colsum
    float* ws = (float*)d_ws;
    float* qk = ws;
    float* v = qk + (size_t)B_ * C4_ * N_;
    float* rowmax = v + (size_t)B_ * C_ * N_;
    float* rowsum = rowmax + (size_t)B_ * N_;
    float* colsum = rowsum + (size_t)B_ * N_;

    const dim3 blk(256);
    proj_kernel<C4_, 8><<<dim3(N_ / 256, C4_ / 8, B_), blk, 0, stream>>>(x, wq, nullptr, qk);
    proj_kernel<C_, 8><<<dim3(N_ / 256, C_ / 8, B_), blk, 0, stream>>>(x, wv, bv, v);
    rowstats_kernel<<<dim3(N_ / 8, B_), blk, 0, stream>>>(qk, rowmax, rowsum);
    colstats_kernel<<<dim3(N_ / 8, B_), blk, 0, stream>>>(qk, rowmax, rowsum, colsum);
    final_kernel<<<dim3(N_ / 4, B_), blk, 0, stream>>>(
        x, qk, v, rowmax, rowsum, colsum, wt, bt, gamma, beta, rmean, rvar, out);
}

// Round 2
// 712.337 us; speedup vs baseline: 13.9554x; 13.9554x over previous
//
#include <hip/hip_runtime.h>
#include <math.h>

namespace {

constexpr int B_ = 4;
constexpr int C_ = 256;
constexpr int C4_ = 64;
constexpr int N_ = 4096;

typedef __attribute__((ext_vector_type(8))) short bf16x8;
typedef __attribute__((ext_vector_type(4))) float f32x4;

__device__ __forceinline__ unsigned short bf16_rne(float f) {
    unsigned u = __float_as_uint(f);
    u += 0x7fffu + ((u >> 16) & 1u);
    return (unsigned short)(u >> 16);
}

// qkT[b, n, o] bf16 = sum_c wq[o,c] * x[b,c,n]
__global__ __launch_bounds__(256) void proj_qkT_kernel(
        const float* __restrict__ x, const float* __restrict__ wq,
        unsigned short* __restrict__ qkT) {
    const int n = blockIdx.x * 256 + threadIdx.x;
    const int o0 = blockIdx.y * 8;
    const int b = blockIdx.z;
    float acc[8] = {};
    const float* xp = x + (size_t)b * C_ * N_ + n;
    const float* wp = wq + (size_t)o0 * C_;
#pragma unroll 4
    for (int c = 0; c < C_; ++c) {
        const float xv = xp[(size_t)c * N_];
#pragma unroll
        for (int j = 0; j < 8; ++j) acc[j] += wp[j * C_ + c] * xv;
    }
    uint4 pk;
    pk.x = bf16_rne(acc[0]) | ((unsigned)bf16_rne(acc[1]) << 16);
    pk.y = bf16_rne(acc[2]) | ((unsigned)bf16_rne(acc[3]) << 16);
    pk.z = bf16_rne(acc[4]) | ((unsigned)bf16_rne(acc[5]) << 16);
    pk.w = bf16_rne(acc[6]) | ((unsigned)bf16_rne(acc[7]) << 16);
    *reinterpret_cast<uint4*>(qkT + ((size_t)b * N_ + n) * C4_ + o0) = pk;
}

// v[b, c, n] bf16 = bv[c] + sum_cc wv[c,cc] * x[b,cc,n]
__global__ __launch_bounds__(256) void proj_v_kernel(
        const float* __restrict__ x, const float* __restrict__ wv,
        const float* __restrict__ bv, unsigned short* __restrict__ v) {
    const int n = blockIdx.x * 256 + threadIdx.x;
    const int o0 = blockIdx.y * 8;
    const int b = blockIdx.z;
    float acc[8];
#pragma unroll
    for (int j = 0; j < 8; ++j) acc[j] = bv[o0 + j];
    const float* xp = x + (size_t)b * C_ * N_ + n;
    const float* wp = wv + (size_t)o0 * C_;
#pragma unroll 4
    for (int c = 0; c < C_; ++c) {
        const float xv = xp[(size_t)c * N_];
#pragma unroll
        for (int j = 0; j < 8; ++j) acc[j] += wp[j * C_ + c] * xv;
    }
#pragma unroll
    for (int j = 0; j < 8; ++j)
        v[((size_t)b * C_ + o0 + j) * N_ + n] = bf16_rne(acc[j]);
}

__global__ __launch_bounds__(256) void cvt_wt_kernel(
        const float* __restrict__ wt, unsigned short* __restrict__ wtb) {
    const int i = (blockIdx.x * 256 + threadIdx.x) * 4;
    const float4 f = *reinterpret_cast<const float4*>(wt + i);
    ushort4 u;
    u.x = bf16_rne(f.x); u.y = bf16_rne(f.y);
    u.z = bf16_rne(f.z); u.w = bf16_rne(f.w);
    *reinterpret_cast<ushort4*>(wtb + i) = u;
}

// Pass 1: per-row online softmax stats via MFMA energy tiles.
__global__ __launch_bounds__(256) void rowstats_kernel(
        const unsigned short* __restrict__ qkT, float* __restrict__ rowmax,
        float* __restrict__ rowsum) {
    const int b = blockIdx.y;
    const int tid = threadIdx.x;
    const int wave = tid >> 6, lane = tid & 63;
    const int quad = lane >> 4, l15 = lane & 15;
    const int n0 = blockIdx.x * 64 + wave * 16;
    const unsigned short* qb = qkT + (size_t)b * N_ * C4_;
    const unsigned short* qrow = qb + (size_t)(n0 + l15) * C4_;
    const bf16x8 a0 = *reinterpret_cast<const bf16x8*>(qrow + quad * 8);
    const bf16x8 a1 = *reinterpret_cast<const bf16x8*>(qrow + 32 + quad * 8);
    float mx[4], sm[4];
#pragma unroll
    for (int r = 0; r < 4; ++r) { mx[r] = -INFINITY; sm[r] = 0.f; }
    for (int m0 = 0; m0 < N_; m0 += 64) {
        f32x4 e[4];
#pragma unroll
        for (int s = 0; s < 4; ++s) {
            const unsigned short* krow = qb + (size_t)(m0 + s * 16 + l15) * C4_;
            const bf16x8 kb0 = *reinterpret_cast<const bf16x8*>(krow + quad * 8);
            const bf16x8 kb1 = *reinterpret_cast<const bf16x8*>(krow + 32 + quad * 8);
            f32x4 z = {0.f, 0.f, 0.f, 0.f};
            z = __builtin_amdgcn_mfma_f32_16x16x32_bf16(a0, kb0, z, 0, 0, 0);
            e[s] = __builtin_amdgcn_mfma_f32_16x16x32_bf16(a1, kb1, z, 0, 0, 0);
        }
#pragma unroll
        for (int r = 0; r < 4; ++r) {
            const float tmax = fmaxf(fmaxf(e[0][r], e[1][r]), fmaxf(e[2][r], e[3][r]));
            const float nm = fmaxf(mx[r], tmax);
            sm[r] = sm[r] * __expf(mx[r] - nm)
                  + __expf(e[0][r] - nm) + __expf(e[1][r] - nm)
                  + __expf(e[2][r] - nm) + __expf(e[3][r] - nm);
            mx[r] = nm;
        }
    }
#pragma unroll
    for (int r = 0; r < 4; ++r) {
#pragma unroll
        for (int k = 1; k <= 8; k <<= 1) {
            const float om = __shfl_xor(mx[r], k, 64);
            const float os = __shfl_xor(sm[r], k, 64);
            const float nm = fmaxf(mx[r], om);
            sm[r] = sm[r] * __expf(mx[r] - nm) + os * __expf(om - nm);
            mx[r] = nm;
        }
        if (l15 == 0) {
            rowmax[(size_t)b * N_ + n0 + quad * 4 + r] = mx[r];
            rowsum[(size_t)b * N_ + n0 + quad * 4 + r] = sm[r];
        }
    }
}

// Pass 2: colsum[b,m] = sum_n exp(e[n,m]-rowmax[n]) / rowsum[n]
__global__ __launch_bounds__(256) void colstats_kernel(
        const unsigned short* __restrict__ qkT, const float* __restrict__ rowmax,
        const float* __restrict__ rowsum, float* __restrict__ colsum) {
    __shared__ float rm_lds[N_];
    __shared__ float rl_lds[N_];
    __shared__ float red[4][4][16];
    const int b = blockIdx.y;
    const int tid = threadIdx.x;
    const int wave = tid >> 6, lane = tid & 63;
    const int quad = lane >> 4, l15 = lane & 15;
    const int m0 = blockIdx.x * 64;
    for (int i = tid; i < N_; i += 256) {
        rm_lds[i] = rowmax[(size_t)b * N_ + i];
        rl_lds[i] = 1.0f / rowsum[(size_t)b * N_ + i];
    }
    __syncthreads();
    const unsigned short* qb = qkT + (size_t)b * N_ * C4_;
    bf16x8 b0[4], b1[4];
#pragma unroll
    for (int s = 0; s < 4; ++s) {
        const unsigned short* krow = qb + (size_t)(m0 + s * 16 + l15) * C4_;
        b0[s] = *reinterpret_cast<const bf16x8*>(krow + quad * 8);
        b1[s] = *reinterpret_cast<const bf16x8*>(krow + 32 + quad * 8);
    }
    float cs[4] = {};
    for (int nt = wave * 16; nt < N_; nt += 64) {
        const unsigned short* qrow = qb + (size_t)(nt + l15) * C4_;
        const bf16x8 a0 = *reinterpret_cast<const bf16x8*>(qrow + quad * 8);
        const bf16x8 a1 = *reinterpret_cast<const bf16x8*>(qrow + 32 + quad * 8);
        float rmv[4], rlv[4];
#pragma unroll
        for (int r = 0; r < 4; ++r) {
            rmv[r] = rm_lds[nt + quad * 4 + r];
            rlv[r] = rl_lds[nt + quad * 4 + r];
        }
#pragma unroll
        for (int s = 0; s < 4; ++s) {
            f32x4 z = {0.f, 0.f, 0.f, 0.f};
            z = __builtin_amdgcn_mfma_f32_16x16x32_bf16(a0, b0[s], z, 0, 0, 0);
            const f32x4 e = __builtin_amdgcn_mfma_f32_16x16x32_bf16(a1, b1[s], z, 0, 0, 0);
#pragma unroll
            for (int r = 0; r < 4; ++r)
                cs[s] += __expf(e[r] - rmv[r]) * rlv[r];
        }
    }
#pragma unroll
    for (int s = 0; s < 4; ++s) {
        cs[s] += __shfl_xor(cs[s], 16, 64);
        cs[s] += __shfl_xor(cs[s], 32, 64);
        if (quad == 0) red[wave][s][l15] = cs[s];
    }
    __syncthreads();
    if (tid < 64)
        colsum[(size_t)b * N_ + m0 + tid] =
            red[0][tid >> 4][tid & 15] + red[1][tid >> 4][tid & 15] +
            red[2][tid >> 4][tid & 15] + red[3][tid >> 4][tid & 15];
}

// Pass 3: recompute P tile-by-tile, PV via MFMA, wt matmul via MFMA, BN+ReLU+res.
__global__ __launch_bounds__(256) void final_kernel(
        const float* __restrict__ x, const unsigned short* __restrict__ qkT,
        const unsigned short* __restrict__ v, const unsigned short* __restrict__ wtb,
        const float* __restrict__ rowmax, const float* __restrict__ rowsum,
        const float* __restrict__ colsum, const float* __restrict__ bt,
        const float* __restrict__ gamma, const float* __restrict__ beta,
        const float* __restrict__ rmean, const float* __restrict__ rvar,
        float* __restrict__ out) {
    __shared__ float ci_lds[N_];                  // 16 KB
    __shared__ unsigned short p_lds[4][16][72];   // 9 KB, +8 pad breaks conflicts
    __shared__ unsigned short dsm_lds[64][264];   // 33 KB, +8 pad
    const int b = blockIdx.y;
    const int tid = threadIdx.x;
    const int wave = tid >> 6, lane = tid & 63;
    const int quad = lane >> 4, l15 = lane & 15;
    const int n0 = blockIdx.x * 64 + wave * 16;
    for (int i = tid; i < N_; i += 256)
        ci_lds[i] = 1.0f / (1e-9f + colsum[(size_t)b * N_ + i]);
    const unsigned short* qb = qkT + (size_t)b * N_ * C4_;
    const unsigned short* qrow = qb + (size_t)(n0 + l15) * C4_;
    const bf16x8 a0 = *reinterpret_cast<const bf16x8*>(qrow + quad * 8);
    const bf16x8 a1 = *reinterpret_cast<const bf16x8*>(qrow + 32 + quad * 8);
    float rmx[4], rli[4];
#pragma unroll
    for (int r = 0; r < 4; ++r) {
        rmx[r] = rowmax[(size_t)b * N_ + n0 + quad * 4 + r];
        rli[r] = 1.0f / rowsum[(size_t)b * N_ + n0 + quad * 4 + r];
    }
    __syncthreads();
    f32x4 acc[16];
#pragma unroll
    for (int ct = 0; ct < 16; ++ct) acc[ct] = (f32x4){0.f, 0.f, 0.f, 0.f};
    const unsigned short* vb = v + (size_t)b * C_ * N_;
    for (int m0 = 0; m0 < N_; m0 += 64) {
#pragma unroll
        for (int s = 0; s < 4; ++s) {
            const unsigned short* krow = qb + (size_t)(m0 + s * 16 + l15) * C4_;
            const bf16x8 kb0 = *reinterpret_cast<const bf16x8*>(krow + quad * 8);
            const bf16x8 kb1 = *reinterpret_cast<const bf16x8*>(krow + 32 + quad * 8);
            f32x4 z = {0.f, 0.f, 0.f, 0.f};
            z = __builtin_amdgcn_mfma_f32_16x16x32_bf16(a0, kb0, z, 0, 0, 0);
            const f32x4 e = __builtin_amdgcn_mfma_f32_16x16x32_bf16(a1, kb1, z, 0, 0, 0);
            const float civ = ci_lds[m0 + s * 16 + l15];
#pragma unroll
            for (int r = 0; r < 4; ++r) {
                const float p = __expf(e[r] - rmx[r]) * rli[r] * civ;
                p_lds[wave][quad * 4 + r][s * 16 + l15] = bf16_rne(p);
            }
        }
        __syncthreads();
        const bf16x8 pa0 = *reinterpret_cast<const bf16x8*>(&p_lds[wave][l15][quad * 8]);
        const bf16x8 pa1 = *reinterpret_cast<const bf16x8*>(&p_lds[wave][l15][32 + quad * 8]);
#pragma unroll
        for (int ct = 0; ct < 16; ++ct) {
            const unsigned short* vrow = vb + (size_t)(ct * 16 + l15) * N_ + m0;
            const bf16x8 vb0 = *reinterpret_cast<const bf16x8*>(vrow + quad * 8);
            const bf16x8 vb1 = *reinterpret_cast<const bf16x8*>(vrow + 32 + quad * 8);
            acc[ct] = __builtin_amdgcn_mfma_f32_16x16x32_bf16(pa0, vb0, acc[ct], 0, 0, 0);
            acc[ct] = __builtin_amdgcn_mfma_f32_16x16x32_bf16(pa1, vb1, acc[ct], 0, 0, 0);
        }
        __syncthreads();
    }
    // dsm = x - x_r  (bf16, A-operand layout rows=local n, cols=c)
#pragma unroll
    for (int ct = 0; ct < 16; ++ct) {
        const int c = ct * 16 + l15;
#pragma unroll
        for (int r = 0; r < 4; ++r) {
            const float xv = x[((size_t)b * C_ + c) * N_ + n0 + quad * 4 + r];
            dsm_lds[wave * 16 + quad * 4 + r][c] = bf16_rne(xv - acc[ct][r]);
        }
    }
    __syncthreads();
    bf16x8 da[8];
#pragma unroll
    for (int k = 0; k < 8; ++k)
        da[k] = *reinterpret_cast<const bf16x8*>(
            &dsm_lds[wave * 16 + l15][k * 32 + quad * 8]);
    f32x4 tacc[16];
#pragma unroll
    for (int ot = 0; ot < 16; ++ot) tacc[ot] = (f32x4){0.f, 0.f, 0.f, 0.f};
#pragma unroll
    for (int ot = 0; ot < 16; ++ot) {
#pragma unroll
        for (int k = 0; k < 8; ++k) {
            const bf16x8 wb = *reinterpret_cast<const bf16x8*>(
                wtb + (size_t)(ot * 16 + l15) * C_ + k * 32 + quad * 8);
            tacc[ot] = __builtin_amdgcn_mfma_f32_16x16x32_bf16(da[k], wb, tacc[ot], 0, 0, 0);
        }
    }
#pragma unroll
    for (int ot = 0; ot < 16; ++ot) {
        const int o = ot * 16 + l15;
        const float g = gamma[o] * rsqrtf(rvar[o] + 1e-5f);
        const float mn = rmean[o], bb = beta[o], bo = bt[o];
#pragma unroll
        for (int r = 0; r < 4; ++r) {
            const float t = tacc[ot][r] + bo;
            const float bn = (t - mn) * g + bb;
            const size_t oi = ((size_t)b * C_ + o) * N_ + n0 + quad * 4 + r;
            out[oi] = x[oi] + fmaxf(bn, 0.f);
        }
    }
}

}  // namespace

extern "C" void kernel_launch(void* const* d_in, const int* in_sizes, int n_in,
                              void* d_out, int out_size, void* d_ws, size_t ws_size,
                              hipStream_t stream) {
    const float* x = (const float*)d_in[0];
    const float* wq = (const float*)d_in[1];
    const float* wv = (const float*)d_in[2];
    const float* bv = (const float*)d_in[3];
    const float* wt = (const float*)d_in[4];
    const float* bt = (const float*)d_in[5];
    const float* gamma = (const float*)d_in[6];
    const float* beta = (const float*)d_in[7];
    const float* rmean = (const float*)d_in[8];
    const float* rvar = (const float*)d_in[9];
    float* out = (float*)d_out;

    // ws layout: qkT bf16 [B,N,64] | v bf16 [B,C,N] | wt bf16 [C,C] | rowmax | rowsum | colsum
    char* base = (char*)d_ws;
    unsigned short* qkT = (unsigned short*)base;                       // 2 MB
    unsigned short* vw = (unsigned short*)(base + (2u << 20));         // 8 MB
    unsigned short* wtb = (unsigned short*)(base + (10u << 20));       // 128 KB
    float* rowmax = (float*)(base + (10u << 20) + (128u << 10));       // 64 KB
    float* rowsum = (float*)(base + (10u << 20) + (192u << 10));       // 64 KB
    float* colsum = (float*)(base + (10u << 20) + (256u << 10));       // 64 KB

    const dim3 blk(256);
    proj_qkT_kernel<<<dim3(N_ / 256, C4_ / 8, B_), blk, 0, stream>>>(x, wq, qkT);
    proj_v_kernel<<<dim3(N_ / 256, C_ / 8, B_), blk, 0, stream>>>(x, wv, bv, vw);
    cvt_wt_kernel<<<dim3(C_ * C_ / 1024), blk, 0, stream>>>(wt, wtb);
    rowstats_kernel<<<dim3(N_ / 64, B_), blk, 0, stream>>>(qkT, rowmax, rowsum);
    colstats_kernel<<<dim3(N_ / 64, B_), blk, 0, stream>>>(qkT, rowmax, rowsum, colsum);
    final_kernel<<<dim3(N_ / 64, B_), blk, 0, stream>>>(
        x, qkT, vw, wtb, rowmax, rowsum, colsum, bt, gamma, beta, rmean, rvar, out);
}

// Round 3
// 673.355 us; speedup vs baseline: 14.7633x; 1.0579x over previous
//
#include <hip/hip_runtime.h>
#include <math.h>

namespace {

constexpr int B_ = 4;
constexpr int C_ = 256;
constexpr int C4_ = 64;
constexpr int N_ = 4096;

typedef __attribute__((ext_vector_type(8))) short bf16x8;
typedef __attribute__((ext_vector_type(4))) float f32x4;

__device__ __forceinline__ unsigned short bf16_rne(float f) {
    unsigned u = __float_as_uint(f);
    u += 0x7fffu + ((u >> 16) & 1u);
    return (unsigned short)(u >> 16);
}

// Convert wq||wv -> wcomb bf16 [320,256], wt -> wtb bf16 [256,256].
__global__ __launch_bounds__(256) void cvt_kernel(
        const float* __restrict__ wq, const float* __restrict__ wv,
        const float* __restrict__ wt, unsigned short* __restrict__ wcomb,
        unsigned short* __restrict__ wtb) {
    const int i = (blockIdx.x * 256 + threadIdx.x) * 4;
    const float* src;
    unsigned short* dst;
    if (i < 16384) { src = wq + i; dst = wcomb + i; }
    else if (i < 81920) { src = wv + (i - 16384); dst = wcomb + i; }
    else { src = wt + (i - 81920); dst = wtb + (i - 81920); }
    const float4 f = *reinterpret_cast<const float4*>(src);
    ushort4 u;
    u.x = bf16_rne(f.x); u.y = bf16_rne(f.y);
    u.z = bf16_rne(f.z); u.w = bf16_rne(f.w);
    *reinterpret_cast<ushort4*>(dst) = u;
}

// MFMA projection: D[n,o] = sum_c x[b,c,n] * wcomb[o,c]; o<64 -> qkT, o>=64 -> v(+bv).
__global__ __launch_bounds__(256) void proj_kernel(
        const float* __restrict__ x, const unsigned short* __restrict__ wcomb,
        const float* __restrict__ bv, unsigned short* __restrict__ qkT,
        unsigned short* __restrict__ v) {
    __shared__ unsigned short xs[2][64][40];  // [buf][n][c-chunk of 32], pad->40
    const int b = blockIdx.y;
    const int n0 = blockIdx.x * 64;
    const int tid = threadIdx.x;
    const int wave = tid >> 6, lane = tid & 63;
    const int quad = lane >> 4, l15 = lane & 15;
    f32x4 acc[20];
#pragma unroll
    for (int ot = 0; ot < 20; ++ot) acc[ot] = (f32x4){0.f, 0.f, 0.f, 0.f};

    auto stage = [&](int c0, int buf) {
#pragma unroll
        for (int i = tid; i < 2048; i += 256) {
            const int c = i >> 6, n = i & 63;
            xs[buf][n][c] = bf16_rne(x[((size_t)b * C_ + c0 + c) * N_ + n0 + n]);
        }
    };
    stage(0, 0);
    __syncthreads();
    for (int ch = 0; ch < 8; ++ch) {
        if (ch < 7) stage((ch + 1) * 32, (ch + 1) & 1);
        const bf16x8 a = *reinterpret_cast<const bf16x8*>(
            &xs[ch & 1][wave * 16 + l15][quad * 8]);
#pragma unroll
        for (int ot = 0; ot < 20; ++ot) {
            const bf16x8 wb = *reinterpret_cast<const bf16x8*>(
                wcomb + (size_t)(ot * 16 + l15) * C_ + ch * 32 + quad * 8);
            acc[ot] = __builtin_amdgcn_mfma_f32_16x16x32_bf16(a, wb, acc[ot], 0, 0, 0);
        }
        __syncthreads();
    }
    const int n = n0 + wave * 16 + quad * 4;
#pragma unroll
    for (int ot = 0; ot < 4; ++ot) {
        const int o = ot * 16 + l15;
#pragma unroll
        for (int r = 0; r < 4; ++r)
            qkT[((size_t)b * N_ + n + r) * C4_ + o] = bf16_rne(acc[ot][r]);
    }
#pragma unroll
    for (int ot = 4; ot < 20; ++ot) {
        const int c = (ot - 4) * 16 + l15;
        const float bb = bv[c];
        ushort4 u;
        u.x = bf16_rne(acc[ot][0] + bb);
        u.y = bf16_rne(acc[ot][1] + bb);
        u.z = bf16_rne(acc[ot][2] + bb);
        u.w = bf16_rne(acc[ot][3] + bb);
        *reinterpret_cast<ushort4*>(&v[((size_t)b * C_ + c) * N_ + n]) = u;
    }
}

// Pass 1: per-row online softmax stats via MFMA energy tiles.
__global__ __launch_bounds__(256) void rowstats_kernel(
        const unsigned short* __restrict__ qkT, float* __restrict__ rowmax,
        float* __restrict__ rowsum) {
    const int b = blockIdx.y;
    const int tid = threadIdx.x;
    const int wave = tid >> 6, lane = tid & 63;
    const int quad = lane >> 4, l15 = lane & 15;
    const int n0 = blockIdx.x * 64 + wave * 16;
    const unsigned short* qb = qkT + (size_t)b * N_ * C4_;
    const unsigned short* qrow = qb + (size_t)(n0 + l15) * C4_;
    const bf16x8 a0 = *reinterpret_cast<const bf16x8*>(qrow + quad * 8);
    const bf16x8 a1 = *reinterpret_cast<const bf16x8*>(qrow + 32 + quad * 8);
    float mx[4], sm[4];
#pragma unroll
    for (int r = 0; r < 4; ++r) { mx[r] = -INFINITY; sm[r] = 0.f; }
    for (int m0 = 0; m0 < N_; m0 += 64) {
        f32x4 e[4];
#pragma unroll
        for (int s = 0; s < 4; ++s) {
            const unsigned short* krow = qb + (size_t)(m0 + s * 16 + l15) * C4_;
            const bf16x8 kb0 = *reinterpret_cast<const bf16x8*>(krow + quad * 8);
            const bf16x8 kb1 = *reinterpret_cast<const bf16x8*>(krow + 32 + quad * 8);
            f32x4 z = {0.f, 0.f, 0.f, 0.f};
            z = __builtin_amdgcn_mfma_f32_16x16x32_bf16(a0, kb0, z, 0, 0, 0);
            e[s] = __builtin_amdgcn_mfma_f32_16x16x32_bf16(a1, kb1, z, 0, 0, 0);
        }
#pragma unroll
        for (int r = 0; r < 4; ++r) {
            const float tmax = fmaxf(fmaxf(e[0][r], e[1][r]), fmaxf(e[2][r], e[3][r]));
            const float nm = fmaxf(mx[r], tmax);
            sm[r] = sm[r] * __expf(mx[r] - nm)
                  + __expf(e[0][r] - nm) + __expf(e[1][r] - nm)
                  + __expf(e[2][r] - nm) + __expf(e[3][r] - nm);
            mx[r] = nm;
        }
    }
#pragma unroll
    for (int r = 0; r < 4; ++r) {
#pragma unroll
        for (int k = 1; k <= 8; k <<= 1) {
            const float om = __shfl_xor(mx[r], k, 64);
            const float os = __shfl_xor(sm[r], k, 64);
            const float nm = fmaxf(mx[r], om);
            sm[r] = sm[r] * __expf(mx[r] - nm) + os * __expf(om - nm);
            mx[r] = nm;
        }
        if (l15 == 0) {
            rowmax[(size_t)b * N_ + n0 + quad * 4 + r] = mx[r];
            rowsum[(size_t)b * N_ + n0 + quad * 4 + r] = sm[r];
        }
    }
}

// Pass 2: colsum[b,m] = sum_n exp(e[n,m]-rowmax[n]) / rowsum[n]
__global__ __launch_bounds__(256) void colstats_kernel(
        const unsigned short* __restrict__ qkT, const float* __restrict__ rowmax,
        const float* __restrict__ rowsum, float* __restrict__ colsum) {
    __shared__ float rm_lds[N_];
    __shared__ float rl_lds[N_];
    __shared__ float red[4][4][16];
    const int b = blockIdx.y;
    const int tid = threadIdx.x;
    const int wave = tid >> 6, lane = tid & 63;
    const int quad = lane >> 4, l15 = lane & 15;
    const int m0 = blockIdx.x * 64;
    for (int i = tid; i < N_; i += 256) {
        rm_lds[i] = rowmax[(size_t)b * N_ + i];
        rl_lds[i] = 1.0f / rowsum[(size_t)b * N_ + i];
    }
    __syncthreads();
    const unsigned short* qb = qkT + (size_t)b * N_ * C4_;
    bf16x8 b0[4], b1[4];
#pragma unroll
    for (int s = 0; s < 4; ++s) {
        const unsigned short* krow = qb + (size_t)(m0 + s * 16 + l15) * C4_;
        b0[s] = *reinterpret_cast<const bf16x8*>(krow + quad * 8);
        b1[s] = *reinterpret_cast<const bf16x8*>(krow + 32 + quad * 8);
    }
    float cs[4] = {};
    for (int nt = wave * 16; nt < N_; nt += 64) {
        const unsigned short* qrow = qb + (size_t)(nt + l15) * C4_;
        const bf16x8 a0 = *reinterpret_cast<const bf16x8*>(qrow + quad * 8);
        const bf16x8 a1 = *reinterpret_cast<const bf16x8*>(qrow + 32 + quad * 8);
        float rmv[4], rlv[4];
#pragma unroll
        for (int r = 0; r < 4; ++r) {
            rmv[r] = rm_lds[nt + quad * 4 + r];
            rlv[r] = rl_lds[nt + quad * 4 + r];
        }
#pragma unroll
        for (int s = 0; s < 4; ++s) {
            f32x4 z = {0.f, 0.f, 0.f, 0.f};
            z = __builtin_amdgcn_mfma_f32_16x16x32_bf16(a0, b0[s], z, 0, 0, 0);
            const f32x4 e = __builtin_amdgcn_mfma_f32_16x16x32_bf16(a1, b1[s], z, 0, 0, 0);
#pragma unroll
            for (int r = 0; r < 4; ++r)
                cs[s] += __expf(e[r] - rmv[r]) * rlv[r];
        }
    }
#pragma unroll
    for (int s = 0; s < 4; ++s) {
        cs[s] += __shfl_xor(cs[s], 16, 64);
        cs[s] += __shfl_xor(cs[s], 32, 64);
        if (quad == 0) red[wave][s][l15] = cs[s];
    }
    __syncthreads();
    if (tid < 64)
        colsum[(size_t)b * N_ + m0 + tid] =
            red[0][tid >> 4][tid & 15] + red[1][tid >> 4][tid & 15] +
            red[2][tid >> 4][tid & 15] + red[3][tid >> 4][tid & 15];
}

// Pass 3: recompute P tile-by-tile (no block barriers in m-loop: p_lds is
// per-wave, same-wave LDS ordering via lgkmcnt), PV via MFMA, wt matmul via
// MFMA, BN+ReLU+residual.
__global__ __launch_bounds__(256) void final_kernel(
        const float* __restrict__ x, const unsigned short* __restrict__ qkT,
        const unsigned short* __restrict__ v, const unsigned short* __restrict__ wtb,
        const float* __restrict__ rowmax, const float* __restrict__ rowsum,
        const float* __restrict__ colsum, const float* __restrict__ bt,
        const float* __restrict__ gamma, const float* __restrict__ beta,
        const float* __restrict__ rmean, const float* __restrict__ rvar,
        float* __restrict__ out) {
    __shared__ float ci_lds[N_];                   // 16 KB
    __shared__ unsigned short p_lds[4][2][16][72]; // 18 KB, per-wave dbl-buffered
    __shared__ unsigned short dsm_lds[64][264];    // 33 KB (per-wave rows)
    const int b = blockIdx.y;
    const int tid = threadIdx.x;
    const int wave = tid >> 6, lane = tid & 63;
    const int quad = lane >> 4, l15 = lane & 15;
    const int n0 = blockIdx.x * 64 + wave * 16;
    for (int i = tid; i < N_; i += 256)
        ci_lds[i] = 1.0f / (1e-9f + colsum[(size_t)b * N_ + i]);
    const unsigned short* qb = qkT + (size_t)b * N_ * C4_;
    const unsigned short* qrow = qb + (size_t)(n0 + l15) * C4_;
    const bf16x8 a0 = *reinterpret_cast<const bf16x8*>(qrow + quad * 8);
    const bf16x8 a1 = *reinterpret_cast<const bf16x8*>(qrow + 32 + quad * 8);
    float rmx[4], rli[4];
#pragma unroll
    for (int r = 0; r < 4; ++r) {
        rmx[r] = rowmax[(size_t)b * N_ + n0 + quad * 4 + r];
        rli[r] = 1.0f / rowsum[(size_t)b * N_ + n0 + quad * 4 + r];
    }
    __syncthreads();
    f32x4 acc[16];
#pragma unroll
    for (int ct = 0; ct < 16; ++ct) acc[ct] = (f32x4){0.f, 0.f, 0.f, 0.f};
    const unsigned short* vb = v + (size_t)b * C_ * N_;
    int buf = 0;
    for (int m0 = 0; m0 < N_; m0 += 64, buf ^= 1) {
#pragma unroll
        for (int s = 0; s < 4; ++s) {
            const unsigned short* krow = qb + (size_t)(m0 + s * 16 + l15) * C4_;
            const bf16x8 kb0 = *reinterpret_cast<const bf16x8*>(krow + quad * 8);
            const bf16x8 kb1 = *reinterpret_cast<const bf16x8*>(krow + 32 + quad * 8);
            f32x4 z = {0.f, 0.f, 0.f, 0.f};
            z = __builtin_amdgcn_mfma_f32_16x16x32_bf16(a0, kb0, z, 0, 0, 0);
            const f32x4 e = __builtin_amdgcn_mfma_f32_16x16x32_bf16(a1, kb1, z, 0, 0, 0);
            const float civ = ci_lds[m0 + s * 16 + l15];
#pragma unroll
            for (int r = 0; r < 4; ++r) {
                const float p = __expf(e[r] - rmx[r]) * rli[r] * civ;
                p_lds[wave][buf][quad * 4 + r][s * 16 + l15] = bf16_rne(p);
            }
        }
        const bf16x8 pa0 =
            *reinterpret_cast<const bf16x8*>(&p_lds[wave][buf][l15][quad * 8]);
        const bf16x8 pa1 =
            *reinterpret_cast<const bf16x8*>(&p_lds[wave][buf][l15][32 + quad * 8]);
#pragma unroll
        for (int ct = 0; ct < 16; ++ct) {
            const unsigned short* vrow = vb + (size_t)(ct * 16 + l15) * N_ + m0;
            const bf16x8 vb0 = *reinterpret_cast<const bf16x8*>(vrow + quad * 8);
            const bf16x8 vb1 = *reinterpret_cast<const bf16x8*>(vrow + 32 + quad * 8);
            acc[ct] = __builtin_amdgcn_mfma_f32_16x16x32_bf16(pa0, vb0, acc[ct], 0, 0, 0);
            acc[ct] = __builtin_amdgcn_mfma_f32_16x16x32_bf16(pa1, vb1, acc[ct], 0, 0, 0);
        }
    }
    // dsm = x - x_r (bf16, per-wave rows; no block barrier needed)
#pragma unroll
    for (int ct = 0; ct < 16; ++ct) {
        const int c = ct * 16 + l15;
        const float4 xv = *reinterpret_cast<const float4*>(
            &x[((size_t)b * C_ + c) * N_ + n0 + quad * 4]);
        const float xvr[4] = {xv.x, xv.y, xv.z, xv.w};
#pragma unroll
        for (int r = 0; r < 4; ++r)
            dsm_lds[wave * 16 + quad * 4 + r][c] = bf16_rne(xvr[r] - acc[ct][r]);
    }
    bf16x8 da[8];
#pragma unroll
    for (int k = 0; k < 8; ++k)
        da[k] = *reinterpret_cast<const bf16x8*>(
            &dsm_lds[wave * 16 + l15][k * 32 + quad * 8]);
    f32x4 tacc[16];
#pragma unroll
    for (int ot = 0; ot < 16; ++ot) tacc[ot] = (f32x4){0.f, 0.f, 0.f, 0.f};
#pragma unroll
    for (int ot = 0; ot < 16; ++ot) {
#pragma unroll
        for (int k = 0; k < 8; ++k) {
            const bf16x8 wb = *reinterpret_cast<const bf16x8*>(
                wtb + (size_t)(ot * 16 + l15) * C_ + k * 32 + quad * 8);
            tacc[ot] = __builtin_amdgcn_mfma_f32_16x16x32_bf16(da[k], wb, tacc[ot], 0, 0, 0);
        }
    }
#pragma unroll
    for (int ot = 0; ot < 16; ++ot) {
        const int o = ot * 16 + l15;
        const float g = gamma[o] * rsqrtf(rvar[o] + 1e-5f);
        const float mn = rmean[o], bb = beta[o], bo = bt[o];
        const size_t oi = ((size_t)b * C_ + o) * N_ + n0 + quad * 4;
        const float4 xo = *reinterpret_cast<const float4*>(&x[oi]);
        float4 res;
        res.x = xo.x + fmaxf((tacc[ot][0] + bo - mn) * g + bb, 0.f);
        res.y = xo.y + fmaxf((tacc[ot][1] + bo - mn) * g + bb, 0.f);
        res.z = xo.z + fmaxf((tacc[ot][2] + bo - mn) * g + bb, 0.f);
        res.w = xo.w + fmaxf((tacc[ot][3] + bo - mn) * g + bb, 0.f);
        *reinterpret_cast<float4*>(&out[oi]) = res;
    }
}

}  // namespace

extern "C" void kernel_launch(void* const* d_in, const int* in_sizes, int n_in,
                              void* d_out, int out_size, void* d_ws, size_t ws_size,
                              hipStream_t stream) {
    const float* x = (const float*)d_in[0];
    const float* wq = (const float*)d_in[1];
    const float* wv = (const float*)d_in[2];
    const float* bv = (const float*)d_in[3];
    const float* wt = (const float*)d_in[4];
    const float* bt = (const float*)d_in[5];
    const float* gamma = (const float*)d_in[6];
    const float* beta = (const float*)d_in[7];
    const float* rmean = (const float*)d_in[8];
    const float* rvar = (const float*)d_in[9];
    float* out = (float*)d_out;

    // ws: qkT bf16 [B,N,64] | v bf16 [B,C,N] | wtb [C,C] | wcomb [320,C] | stats
    char* base = (char*)d_ws;
    unsigned short* qkT = (unsigned short*)base;                        // 2 MB
    unsigned short* vw = (unsigned short*)(base + (2u << 20));          // 8 MB
    unsigned short* wtb = (unsigned short*)(base + (10u << 20));        // 128 KB
    unsigned short* wcomb = (unsigned short*)(base + (10u << 20) + (128u << 10)); // 160 KB
    float* rowmax = (float*)(base + (10u << 20) + (288u << 10));        // 64 KB
    float* rowsum = (float*)(base + (10u << 20) + (352u << 10));        // 64 KB
    float* colsum = (float*)(base + (10u << 20) + (416u << 10));        // 64 KB

    const dim3 blk(256);
    cvt_kernel<<<dim3(144), blk, 0, stream>>>(wq, wv, wt, wcomb, wtb);
    proj_kernel<<<dim3(N_ / 64, B_), blk, 0, stream>>>(x, wcomb, bv, qkT, vw);
    rowstats_kernel<<<dim3(N_ / 64, B_), blk, 0, stream>>>(qkT, rowmax, rowsum);
    colstats_kernel<<<dim3(N_ / 64, B_), blk, 0, stream>>>(qkT, rowmax, rowsum, colsum);
    final_kernel<<<dim3(N_ / 64, B_), blk, 0, stream>>>(
        x, qkT, vw, wtb, rowmax, rowsum, colsum, bt, gamma, beta, rmean, rvar, out);
}

// Round 4
// 495.868 us; speedup vs baseline: 20.0476x; 1.3579x over previous
//
#include <hip/hip_runtime.h>
#include <math.h>

namespace {

constexpr int B_ = 4;
constexpr int C_ = 256;
constexpr int C4_ = 64;
constexpr int N_ = 4096;

typedef __attribute__((ext_vector_type(8))) short bf16x8;
typedef __attribute__((ext_vector_type(4))) float f32x4;

__device__ __forceinline__ unsigned short bf16_rne(float f) {
    unsigned u = __float_as_uint(f);
    u += 0x7fffu + ((u >> 16) & 1u);
    return (unsigned short)(u >> 16);
}

// Convert wq||wv -> wcomb bf16 [320,256], wt -> wtb bf16 [256,256].
__global__ __launch_bounds__(256) void cvt_kernel(
        const float* __restrict__ wq, const float* __restrict__ wv,
        const float* __restrict__ wt, unsigned short* __restrict__ wcomb,
        unsigned short* __restrict__ wtb) {
    const int i = (blockIdx.x * 256 + threadIdx.x) * 4;
    const float* src;
    unsigned short* dst;
    if (i < 16384) { src = wq + i; dst = wcomb + i; }
    else if (i < 81920) { src = wv + (i - 16384); dst = wcomb + i; }
    else { src = wt + (i - 81920); dst = wtb + (i - 81920); }
    const float4 f = *reinterpret_cast<const float4*>(src);
    ushort4 u;
    u.x = bf16_rne(f.x); u.y = bf16_rne(f.y);
    u.z = bf16_rne(f.z); u.w = bf16_rne(f.w);
    *reinterpret_cast<ushort4*>(dst) = u;
}

// MFMA projection, o-split by 2: D[n,o] = sum_c x[b,c,n]*wcomb[o,c].
__global__ __launch_bounds__(256) void proj_kernel(
        const float* __restrict__ x, const unsigned short* __restrict__ wcomb,
        const float* __restrict__ bv, unsigned short* __restrict__ qkT,
        unsigned short* __restrict__ v) {
    __shared__ unsigned short xs[2][64][40];
    const int b = blockIdx.z, half = blockIdx.y;
    const int n0 = blockIdx.x * 64;
    const int tid = threadIdx.x;
    const int wave = tid >> 6, lane = tid & 63;
    const int quad = lane >> 4, l15 = lane & 15;
    f32x4 acc[10];
#pragma unroll
    for (int ot = 0; ot < 10; ++ot) acc[ot] = (f32x4){0.f, 0.f, 0.f, 0.f};
    auto stage = [&](int c0, int buf) {
#pragma unroll
        for (int i = tid; i < 2048; i += 256) {
            const int c = i >> 6, n = i & 63;
            xs[buf][n][c] = bf16_rne(x[((size_t)b * C_ + c0 + c) * N_ + n0 + n]);
        }
    };
    stage(0, 0);
    __syncthreads();
    for (int ch = 0; ch < 8; ++ch) {
        if (ch < 7) stage((ch + 1) * 32, (ch + 1) & 1);
        const bf16x8 a = *reinterpret_cast<const bf16x8*>(
            &xs[ch & 1][wave * 16 + l15][quad * 8]);
#pragma unroll
        for (int ot = 0; ot < 10; ++ot) {
            const int gro = half * 10 + ot;
            const bf16x8 wb = *reinterpret_cast<const bf16x8*>(
                wcomb + (size_t)(gro * 16 + l15) * C_ + ch * 32 + quad * 8);
            acc[ot] = __builtin_amdgcn_mfma_f32_16x16x32_bf16(a, wb, acc[ot], 0, 0, 0);
        }
        __syncthreads();
    }
    const int n = n0 + wave * 16 + quad * 4;
#pragma unroll
    for (int ot = 0; ot < 10; ++ot) {
        const int gro = half * 10 + ot;
        if (gro < 4) {
            const int o = gro * 16 + l15;
#pragma unroll
            for (int r = 0; r < 4; ++r)
                qkT[((size_t)b * N_ + n + r) * C4_ + o] = bf16_rne(acc[ot][r]);
        } else {
            const int c = (gro - 4) * 16 + l15;
            const float bb = bv[c];
            ushort4 u;
            u.x = bf16_rne(acc[ot][0] + bb);
            u.y = bf16_rne(acc[ot][1] + bb);
            u.z = bf16_rne(acc[ot][2] + bb);
            u.w = bf16_rne(acc[ot][3] + bb);
            *reinterpret_cast<ushort4*>(&v[((size_t)b * C_ + c) * N_ + n]) = u;
        }
    }
}

// rowsuminv[b,n] = 1 / sum_m exp(e[n,m])   (no max-shift; e bounded ~ +-30)
__global__ __launch_bounds__(512) void rowsum_kernel(
        const unsigned short* __restrict__ qkT, float* __restrict__ rowsuminv) {
    __shared__ float red[2][4][16];
    const int b = blockIdx.y;
    const int tid = threadIdx.x;
    const int wave = tid >> 6, lane = tid & 63;
    const int ws = wave & 3, grp = wave >> 2;
    const int quad = lane >> 4, l15 = lane & 15;
    const int n0 = blockIdx.x * 64 + ws * 16;
    const unsigned short* qb = qkT + (size_t)b * N_ * C4_;
    const unsigned short* qrow = qb + (size_t)(n0 + l15) * C4_;
    const bf16x8 a0 = *reinterpret_cast<const bf16x8*>(qrow + quad * 8);
    const bf16x8 a1 = *reinterpret_cast<const bf16x8*>(qrow + 32 + quad * 8);
    float cs[4] = {};
    for (int mt = grp; mt < N_ / 64; mt += 2) {
        const int m0 = mt * 64;
#pragma unroll
        for (int s = 0; s < 4; ++s) {
            const unsigned short* krow = qb + (size_t)(m0 + s * 16 + l15) * C4_;
            const bf16x8 kb0 = *reinterpret_cast<const bf16x8*>(krow + quad * 8);
            const bf16x8 kb1 = *reinterpret_cast<const bf16x8*>(krow + 32 + quad * 8);
            f32x4 z = {0.f, 0.f, 0.f, 0.f};
            z = __builtin_amdgcn_mfma_f32_16x16x32_bf16(a0, kb0, z, 0, 0, 0);
            const f32x4 e = __builtin_amdgcn_mfma_f32_16x16x32_bf16(a1, kb1, z, 0, 0, 0);
#pragma unroll
            for (int r = 0; r < 4; ++r) cs[r] += __expf(e[r]);
        }
    }
#pragma unroll
    for (int r = 0; r < 4; ++r) {
#pragma unroll
        for (int k = 1; k <= 8; k <<= 1) cs[r] += __shfl_xor(cs[r], k, 64);
        if (l15 == 0) red[grp][ws][quad * 4 + r] = cs[r];
    }
    __syncthreads();
    if (tid < 64) {
        const int s2 = tid >> 4, row = tid & 15;
        const float sum = red[0][s2][row] + red[1][s2][row];
        rowsuminv[(size_t)b * N_ + blockIdx.x * 64 + s2 * 16 + row] = 1.0f / sum;
    }
}

// colsuminv[b,m] = 1 / (1e-9 + sum_n exp(e[n,m]) * rowsuminv[n])
__global__ __launch_bounds__(512) void colsum_kernel(
        const unsigned short* __restrict__ qkT, const float* __restrict__ rowsuminv,
        float* __restrict__ colsuminv) {
    __shared__ float rl[N_];
    __shared__ float red[8][4][16];
    const int b = blockIdx.y;
    const int tid = threadIdx.x;
    const int wave = tid >> 6, lane = tid & 63;
    const int quad = lane >> 4, l15 = lane & 15;
    const int m0 = blockIdx.x * 64;
    for (int i = tid; i < N_; i += 512) rl[i] = rowsuminv[(size_t)b * N_ + i];
    __syncthreads();
    const unsigned short* qb = qkT + (size_t)b * N_ * C4_;
    bf16x8 b0[4], b1[4];
#pragma unroll
    for (int s = 0; s < 4; ++s) {
        const unsigned short* krow = qb + (size_t)(m0 + s * 16 + l15) * C4_;
        b0[s] = *reinterpret_cast<const bf16x8*>(krow + quad * 8);
        b1[s] = *reinterpret_cast<const bf16x8*>(krow + 32 + quad * 8);
    }
    float cs[4] = {};
    for (int nt = wave * 16; nt < N_; nt += 128) {
        const unsigned short* qrow = qb + (size_t)(nt + l15) * C4_;
        const bf16x8 a0 = *reinterpret_cast<const bf16x8*>(qrow + quad * 8);
        const bf16x8 a1 = *reinterpret_cast<const bf16x8*>(qrow + 32 + quad * 8);
        float rlv[4];
#pragma unroll
        for (int r = 0; r < 4; ++r) rlv[r] = rl[nt + quad * 4 + r];
#pragma unroll
        for (int s = 0; s < 4; ++s) {
            f32x4 z = {0.f, 0.f, 0.f, 0.f};
            z = __builtin_amdgcn_mfma_f32_16x16x32_bf16(a0, b0[s], z, 0, 0, 0);
            const f32x4 e = __builtin_amdgcn_mfma_f32_16x16x32_bf16(a1, b1[s], z, 0, 0, 0);
#pragma unroll
            for (int r = 0; r < 4; ++r) cs[s] += __expf(e[r]) * rlv[r];
        }
    }
#pragma unroll
    for (int s = 0; s < 4; ++s) {
        cs[s] += __shfl_xor(cs[s], 16, 64);
        cs[s] += __shfl_xor(cs[s], 32, 64);
        if (quad == 0) red[wave][s][l15] = cs[s];
    }
    __syncthreads();
    if (tid < 64) {
        const int s2 = tid >> 4, l = tid & 15;
        float sum = 0.f;
#pragma unroll
        for (int w = 0; w < 8; ++w) sum += red[w][s2][l];
        colsuminv[(size_t)b * N_ + m0 + s2 * 16 + l] = 1.0f / (1e-9f + sum);
    }
}

// Final: recompute P per m-tile (waves split m), PV MFMA, merge, wt MFMA, BN+ReLU+res.
__global__ __launch_bounds__(512) void final_kernel(
        const float* __restrict__ x, const unsigned short* __restrict__ qkT,
        const unsigned short* __restrict__ v, const unsigned short* __restrict__ wtb,
        const float* __restrict__ rowsuminv, const float* __restrict__ colsuminv,
        const float* __restrict__ bt, const float* __restrict__ gamma,
        const float* __restrict__ beta, const float* __restrict__ rmean,
        const float* __restrict__ rvar, float* __restrict__ out) {
    __shared__ union {
        struct { float ci[N_]; unsigned short p[8][16][72]; } a;  // 16K + 18K
        float red[4][8][16][16];                                  // 32K
    } sh;
    __shared__ unsigned short dsm[64][264];  // 33K
    const int b = blockIdx.y;
    const int tid = threadIdx.x;
    const int wave = tid >> 6, lane = tid & 63;
    const int ws = wave & 3, grp = wave >> 2;
    const int quad = lane >> 4, l15 = lane & 15;
    const int n0 = blockIdx.x * 64 + ws * 16;
    for (int i = tid; i < N_; i += 512) sh.a.ci[i] = colsuminv[(size_t)b * N_ + i];
    const unsigned short* qb = qkT + (size_t)b * N_ * C4_;
    const unsigned short* qrow = qb + (size_t)(n0 + l15) * C4_;
    const bf16x8 a0 = *reinterpret_cast<const bf16x8*>(qrow + quad * 8);
    const bf16x8 a1 = *reinterpret_cast<const bf16x8*>(qrow + 32 + quad * 8);
    float rli[4];
#pragma unroll
    for (int r = 0; r < 4; ++r)
        rli[r] = rowsuminv[(size_t)b * N_ + n0 + quad * 4 + r];
    __syncthreads();
    f32x4 acc[16];
#pragma unroll
    for (int ct = 0; ct < 16; ++ct) acc[ct] = (f32x4){0.f, 0.f, 0.f, 0.f};
    const unsigned short* vb = v + (size_t)b * C_ * N_;
    for (int mt = grp; mt < N_ / 64; mt += 2) {
        const int m0 = mt * 64;
#pragma unroll
        for (int s = 0; s < 4; ++s) {
            const unsigned short* krow = qb + (size_t)(m0 + s * 16 + l15) * C4_;
            const bf16x8 kb0 = *reinterpret_cast<const bf16x8*>(krow + quad * 8);
            const bf16x8 kb1 = *reinterpret_cast<const bf16x8*>(krow + 32 + quad * 8);
            f32x4 z = {0.f, 0.f, 0.f, 0.f};
            z = __builtin_amdgcn_mfma_f32_16x16x32_bf16(a0, kb0, z, 0, 0, 0);
            const f32x4 e = __builtin_amdgcn_mfma_f32_16x16x32_bf16(a1, kb1, z, 0, 0, 0);
            const float civ = sh.a.ci[m0 + s * 16 + l15];
#pragma unroll
            for (int r = 0; r < 4; ++r) {
                const float p = __expf(e[r]) * rli[r] * civ;
                sh.a.p[wave][quad * 4 + r][s * 16 + l15] = bf16_rne(p);
            }
        }
        // same-wave LDS ordering (in-order DS) makes this safe without barriers
        const bf16x8 pa0 = *reinterpret_cast<const bf16x8*>(&sh.a.p[wave][l15][quad * 8]);
        const bf16x8 pa1 = *reinterpret_cast<const bf16x8*>(&sh.a.p[wave][l15][32 + quad * 8]);
#pragma unroll
        for (int ct = 0; ct < 16; ++ct) {
            const unsigned short* vrow = vb + (size_t)(ct * 16 + l15) * N_ + m0;
            const bf16x8 vb0 = *reinterpret_cast<const bf16x8*>(vrow + quad * 8);
            const bf16x8 vb1 = *reinterpret_cast<const bf16x8*>(vrow + 32 + quad * 8);
            acc[ct] = __builtin_amdgcn_mfma_f32_16x16x32_bf16(pa0, vb0, acc[ct], 0, 0, 0);
            acc[ct] = __builtin_amdgcn_mfma_f32_16x16x32_bf16(pa1, vb1, acc[ct], 0, 0, 0);
        }
    }
    __syncthreads();
    // merge grp1 partial acc into grp0 (2 chunks of 8 ct through red)
#pragma unroll
    for (int chunk = 0; chunk < 2; ++chunk) {
        if (grp == 1) {
#pragma unroll
            for (int j = 0; j < 8; ++j) {
                const int ct = chunk * 8 + j;
#pragma unroll
                for (int r = 0; r < 4; ++r)
                    sh.red[ws][j][quad * 4 + r][l15] = acc[ct][r];
            }
        }
        __syncthreads();
        if (grp == 0) {
#pragma unroll
            for (int j = 0; j < 8; ++j) {
                const int ct = chunk * 8 + j;
#pragma unroll
                for (int r = 0; r < 4; ++r)
                    acc[ct][r] += sh.red[ws][j][quad * 4 + r][l15];
            }
        }
        __syncthreads();
    }
    if (grp == 0) {
#pragma unroll
        for (int ct = 0; ct < 16; ++ct) {
            const int c = ct * 16 + l15;
            const float4 xv = *reinterpret_cast<const float4*>(
                &x[((size_t)b * C_ + c) * N_ + n0 + quad * 4]);
            const float xvr[4] = {xv.x, xv.y, xv.z, xv.w};
#pragma unroll
            for (int r = 0; r < 4; ++r)
                dsm[ws * 16 + quad * 4 + r][c] = bf16_rne(xvr[r] - acc[ct][r]);
        }
    }
    __syncthreads();
    // wt GEMM: 4 strips x 2 o-halves across the 8 waves
    bf16x8 da[8];
#pragma unroll
    for (int k = 0; k < 8; ++k)
        da[k] = *reinterpret_cast<const bf16x8*>(&dsm[ws * 16 + l15][k * 32 + quad * 8]);
    f32x4 tacc[8];
#pragma unroll
    for (int j = 0; j < 8; ++j) tacc[j] = (f32x4){0.f, 0.f, 0.f, 0.f};
#pragma unroll
    for (int j = 0; j < 8; ++j) {
        const int ot = grp * 8 + j;
#pragma unroll
        for (int k = 0; k < 8; ++k) {
            const bf16x8 wb = *reinterpret_cast<const bf16x8*>(
                wtb + (size_t)(ot * 16 + l15) * C_ + k * 32 + quad * 8);
            tacc[j] = __builtin_amdgcn_mfma_f32_16x16x32_bf16(da[k], wb, tacc[j], 0, 0, 0);
        }
    }
#pragma unroll
    for (int j = 0; j < 8; ++j) {
        const int o = (grp * 8 + j) * 16 + l15;
        const float g = gamma[o] * rsqrtf(rvar[o] + 1e-5f);
        const float mn = rmean[o], bbet = beta[o], bo = bt[o];
        const size_t oi = ((size_t)b * C_ + o) * N_ + n0 + quad * 4;
        const float4 xo = *reinterpret_cast<const float4*>(&x[oi]);
        float4 res;
        res.x = xo.x + fmaxf((tacc[j][0] + bo - mn) * g + bbet, 0.f);
        res.y = xo.y + fmaxf((tacc[j][1] + bo - mn) * g + bbet, 0.f);
        res.z = xo.z + fmaxf((tacc[j][2] + bo - mn) * g + bbet, 0.f);
        res.w = xo.w + fmaxf((tacc[j][3] + bo - mn) * g + bbet, 0.f);
        *reinterpret_cast<float4*>(&out[oi]) = res;
    }
}

}  // namespace

extern "C" void kernel_launch(void* const* d_in, const int* in_sizes, int n_in,
                              void* d_out, int out_size, void* d_ws, size_t ws_size,
                              hipStream_t stream) {
    const float* x = (const float*)d_in[0];
    const float* wq = (const float*)d_in[1];
    const float* wv = (const float*)d_in[2];
    const float* bv = (const float*)d_in[3];
    const float* wt = (const float*)d_in[4];
    const float* bt = (const float*)d_in[5];
    const float* gamma = (const float*)d_in[6];
    const float* beta = (const float*)d_in[7];
    const float* rmean = (const float*)d_in[8];
    const float* rvar = (const float*)d_in[9];
    float* out = (float*)d_out;

    char* base = (char*)d_ws;
    unsigned short* qkT = (unsigned short*)base;                        // 2 MB
    unsigned short* vw = (unsigned short*)(base + (2u << 20));          // 8 MB
    unsigned short* wtb = (unsigned short*)(base + (10u << 20));        // 128 KB
    unsigned short* wcomb = (unsigned short*)(base + (10u << 20) + (128u << 10));
    float* rowsuminv = (float*)(base + (10u << 20) + (288u << 10));     // 64 KB
    float* colsuminv = (float*)(base + (10u << 20) + (352u << 10));     // 64 KB

    cvt_kernel<<<dim3(144), dim3(256), 0, stream>>>(wq, wv, wt, wcomb, wtb);
    proj_kernel<<<dim3(N_ / 64, 2, B_), dim3(256), 0, stream>>>(x, wcomb, bv, qkT, vw);
    rowsum_kernel<<<dim3(N_ / 64, B_), dim3(512), 0, stream>>>(qkT, rowsuminv);
    colsum_kernel<<<dim3(N_ / 64, B_), dim3(512), 0, stream>>>(qkT, rowsuminv, colsuminv);
    final_kernel<<<dim3(N_ / 64, B_), dim3(512), 0, stream>>>(
        x, qkT, vw, wtb, rowsuminv, colsuminv, bt, gamma, beta, rmean, rvar, out);
}

// Round 5
// 493.483 us; speedup vs baseline: 20.1445x; 1.0048x over previous
//
#include <hip/hip_runtime.h>
#include <math.h>

namespace {

constexpr int B_ = 4;
constexpr int C_ = 256;
constexpr int C4_ = 64;
constexpr int N_ = 4096;

typedef __attribute__((ext_vector_type(8))) short bf16x8;
typedef __attribute__((ext_vector_type(4))) float f32x4;

__device__ __forceinline__ unsigned short bf16_rne(float f) {
    unsigned u = __float_as_uint(f);
    u += 0x7fffu + ((u >> 16) & 1u);
    return (unsigned short)(u >> 16);
}

// Convert wq||wv -> wcomb bf16 [320,256], wt -> wtb bf16 [256,256].
__global__ __launch_bounds__(256) void cvt_kernel(
        const float* __restrict__ wq, const float* __restrict__ wv,
        const float* __restrict__ wt, unsigned short* __restrict__ wcomb,
        unsigned short* __restrict__ wtb) {
    const int i = (blockIdx.x * 256 + threadIdx.x) * 4;
    const float* src;
    unsigned short* dst;
    if (i < 16384) { src = wq + i; dst = wcomb + i; }
    else if (i < 81920) { src = wv + (i - 16384); dst = wcomb + i; }
    else { src = wt + (i - 81920); dst = wtb + (i - 81920); }
    const float4 f = *reinterpret_cast<const float4*>(src);
    ushort4 u;
    u.x = bf16_rne(f.x); u.y = bf16_rne(f.y);
    u.z = bf16_rne(f.z); u.w = bf16_rne(f.w);
    *reinterpret_cast<ushort4*>(dst) = u;
}

// MFMA projection, o-split by 4: D[n,o] = sum_c x[b,c,n]*wcomb[o,c].
__global__ __launch_bounds__(256) void proj_kernel(
        const float* __restrict__ x, const unsigned short* __restrict__ wcomb,
        const float* __restrict__ bv, unsigned short* __restrict__ qkT,
        unsigned short* __restrict__ v) {
    __shared__ unsigned short xs[2][64][40];
    const int b = blockIdx.z, quarter = blockIdx.y;
    const int n0 = blockIdx.x * 64;
    const int tid = threadIdx.x;
    const int wave = tid >> 6, lane = tid & 63;
    const int quad = lane >> 4, l15 = lane & 15;
    f32x4 acc[5];
#pragma unroll
    for (int ot = 0; ot < 5; ++ot) acc[ot] = (f32x4){0.f, 0.f, 0.f, 0.f};
    auto stage = [&](int c0, int buf) {
#pragma unroll
        for (int i = tid; i < 2048; i += 256) {
            const int c = i >> 6, n = i & 63;
            xs[buf][n][c] = bf16_rne(x[((size_t)b * C_ + c0 + c) * N_ + n0 + n]);
        }
    };
    stage(0, 0);
    __syncthreads();
    for (int ch = 0; ch < 8; ++ch) {
        if (ch < 7) stage((ch + 1) * 32, (ch + 1) & 1);
        const bf16x8 a = *reinterpret_cast<const bf16x8*>(
            &xs[ch & 1][wave * 16 + l15][quad * 8]);
#pragma unroll
        for (int ot = 0; ot < 5; ++ot) {
            const int gro = quarter * 5 + ot;
            const bf16x8 wb = *reinterpret_cast<const bf16x8*>(
                wcomb + (size_t)(gro * 16 + l15) * C_ + ch * 32 + quad * 8);
            acc[ot] = __builtin_amdgcn_mfma_f32_16x16x32_bf16(a, wb, acc[ot], 0, 0, 0);
        }
        __syncthreads();
    }
    const int n = n0 + wave * 16 + quad * 4;
#pragma unroll
    for (int ot = 0; ot < 5; ++ot) {
        const int gro = quarter * 5 + ot;
        if (gro < 4) {
            const int o = gro * 16 + l15;
#pragma unroll
            for (int r = 0; r < 4; ++r)
                qkT[((size_t)b * N_ + n + r) * C4_ + o] = bf16_rne(acc[ot][r]);
        } else {
            const int c = (gro - 4) * 16 + l15;
            const float bb = bv[c];
            ushort4 u;
            u.x = bf16_rne(acc[ot][0] + bb);
            u.y = bf16_rne(acc[ot][1] + bb);
            u.z = bf16_rne(acc[ot][2] + bb);
            u.w = bf16_rne(acc[ot][3] + bb);
            *reinterpret_cast<ushort4*>(&v[((size_t)b * C_ + c) * N_ + n]) = u;
        }
    }
}

// rowsuminv[b,n] = 1 / sum_m exp(e[n,m])   (no max-shift; e bounded)
__global__ __launch_bounds__(1024, 4) void rowsum_kernel(
        const unsigned short* __restrict__ qkT, float* __restrict__ rowsuminv) {
    __shared__ float red[4][4][16];
    const int b = blockIdx.y;
    const int tid = threadIdx.x;
    const int wave = tid >> 6, lane = tid & 63;
    const int ws = wave & 3, grp = wave >> 2;  // grp in 0..3
    const int quad = lane >> 4, l15 = lane & 15;
    const int n0 = blockIdx.x * 64 + ws * 16;
    const unsigned short* qb = qkT + (size_t)b * N_ * C4_;
    const unsigned short* qrow = qb + (size_t)(n0 + l15) * C4_;
    const bf16x8 a0 = *reinterpret_cast<const bf16x8*>(qrow + quad * 8);
    const bf16x8 a1 = *reinterpret_cast<const bf16x8*>(qrow + 32 + quad * 8);
    float cs[4] = {};
    for (int mt = grp; mt < N_ / 64; mt += 4) {
        const int m0 = mt * 64;
#pragma unroll
        for (int s = 0; s < 4; ++s) {
            const unsigned short* krow = qb + (size_t)(m0 + s * 16 + l15) * C4_;
            const bf16x8 kb0 = *reinterpret_cast<const bf16x8*>(krow + quad * 8);
            const bf16x8 kb1 = *reinterpret_cast<const bf16x8*>(krow + 32 + quad * 8);
            f32x4 z = {0.f, 0.f, 0.f, 0.f};
            z = __builtin_amdgcn_mfma_f32_16x16x32_bf16(a0, kb0, z, 0, 0, 0);
            const f32x4 e = __builtin_amdgcn_mfma_f32_16x16x32_bf16(a1, kb1, z, 0, 0, 0);
#pragma unroll
            for (int r = 0; r < 4; ++r) cs[r] += __expf(e[r]);
        }
    }
#pragma unroll
    for (int r = 0; r < 4; ++r) {
#pragma unroll
        for (int k = 1; k <= 8; k <<= 1) cs[r] += __shfl_xor(cs[r], k, 64);
        if (l15 == 0) red[grp][ws][quad * 4 + r] = cs[r];
    }
    __syncthreads();
    if (tid < 64) {
        const int s2 = tid >> 4, row = tid & 15;
        const float sum = red[0][s2][row] + red[1][s2][row] +
                          red[2][s2][row] + red[3][s2][row];
        rowsuminv[(size_t)b * N_ + blockIdx.x * 64 + s2 * 16 + row] = 1.0f / sum;
    }
}

// colsuminv[b,m] = 1 / (1e-9 + sum_n exp(e[n,m]) * rowsuminv[n])
__global__ __launch_bounds__(1024, 4) void colsum_kernel(
        const unsigned short* __restrict__ qkT, const float* __restrict__ rowsuminv,
        float* __restrict__ colsuminv) {
    __shared__ float rl[N_];
    __shared__ float red[16][4][16];
    const int b = blockIdx.y;
    const int tid = threadIdx.x;
    const int wave = tid >> 6, lane = tid & 63;
    const int quad = lane >> 4, l15 = lane & 15;
    const int m0 = blockIdx.x * 64;
    for (int i = tid; i < N_; i += 1024) rl[i] = rowsuminv[(size_t)b * N_ + i];
    __syncthreads();
    const unsigned short* qb = qkT + (size_t)b * N_ * C4_;
    bf16x8 b0[4], b1[4];
#pragma unroll
    for (int s = 0; s < 4; ++s) {
        const unsigned short* krow = qb + (size_t)(m0 + s * 16 + l15) * C4_;
        b0[s] = *reinterpret_cast<const bf16x8*>(krow + quad * 8);
        b1[s] = *reinterpret_cast<const bf16x8*>(krow + 32 + quad * 8);
    }
    float cs[4] = {};
    for (int nt = wave * 16; nt < N_; nt += 256) {
        const unsigned short* qrow = qb + (size_t)(nt + l15) * C4_;
        const bf16x8 a0 = *reinterpret_cast<const bf16x8*>(qrow + quad * 8);
        const bf16x8 a1 = *reinterpret_cast<const bf16x8*>(qrow + 32 + quad * 8);
        float rlv[4];
#pragma unroll
        for (int r = 0; r < 4; ++r) rlv[r] = rl[nt + quad * 4 + r];
#pragma unroll
        for (int s = 0; s < 4; ++s) {
            f32x4 z = {0.f, 0.f, 0.f, 0.f};
            z = __builtin_amdgcn_mfma_f32_16x16x32_bf16(a0, b0[s], z, 0, 0, 0);
            const f32x4 e = __builtin_amdgcn_mfma_f32_16x16x32_bf16(a1, b1[s], z, 0, 0, 0);
#pragma unroll
            for (int r = 0; r < 4; ++r) cs[s] += __expf(e[r]) * rlv[r];
        }
    }
#pragma unroll
    for (int s = 0; s < 4; ++s) {
        cs[s] += __shfl_xor(cs[s], 16, 64);
        cs[s] += __shfl_xor(cs[s], 32, 64);
        if (quad == 0) red[wave][s][l15] = cs[s];
    }
    __syncthreads();
    if (tid < 64) {
        const int s2 = tid >> 4, l = tid & 15;
        float sum = 0.f;
#pragma unroll
        for (int w = 0; w < 16; ++w) sum += red[w][s2][l];
        colsuminv[(size_t)b * N_ + m0 + s2 * 16 + l] = 1.0f / (1e-9f + sum);
    }
}

// Final: 16 waves = 4 n-strips x 4-way m-split. Recompute P per m-tile,
// PV MFMA, LDS tree-merge, wt MFMA, BN+ReLU+residual.
__global__ __launch_bounds__(1024, 4) void final_kernel(
        const float* __restrict__ x, const unsigned short* __restrict__ qkT,
        const unsigned short* __restrict__ v, const unsigned short* __restrict__ wtb,
        const float* __restrict__ rowsuminv, const float* __restrict__ colsuminv,
        const float* __restrict__ bt, const float* __restrict__ gamma,
        const float* __restrict__ beta, const float* __restrict__ rmean,
        const float* __restrict__ rvar, float* __restrict__ out) {
    __shared__ union {
        struct { float ci[N_]; unsigned short p[16][16][72]; } a;  // 16K + 36K
        float red[2][4][8][16][16];                                // 64K
    } sh;
    __shared__ unsigned short dsm[64][264];  // 33K
    const int b = blockIdx.y;
    const int tid = threadIdx.x;
    const int wave = tid >> 6, lane = tid & 63;
    const int ws = wave & 3, grp = wave >> 2;  // grp 0..3
    const int quad = lane >> 4, l15 = lane & 15;
    const int n0 = blockIdx.x * 64 + ws * 16;
    for (int i = tid; i < N_; i += 1024) sh.a.ci[i] = colsuminv[(size_t)b * N_ + i];
    const unsigned short* qb = qkT + (size_t)b * N_ * C4_;
    const unsigned short* qrow = qb + (size_t)(n0 + l15) * C4_;
    const bf16x8 a0 = *reinterpret_cast<const bf16x8*>(qrow + quad * 8);
    const bf16x8 a1 = *reinterpret_cast<const bf16x8*>(qrow + 32 + quad * 8);
    float rli[4];
#pragma unroll
    for (int r = 0; r < 4; ++r)
        rli[r] = rowsuminv[(size_t)b * N_ + n0 + quad * 4 + r];
    __syncthreads();
    f32x4 acc[16];
#pragma unroll
    for (int ct = 0; ct < 16; ++ct) acc[ct] = (f32x4){0.f, 0.f, 0.f, 0.f};
    const unsigned short* vb = v + (size_t)b * C_ * N_;
    for (int mt = grp; mt < N_ / 64; mt += 4) {
        const int m0 = mt * 64;
#pragma unroll
        for (int s = 0; s < 4; ++s) {
            const unsigned short* krow = qb + (size_t)(m0 + s * 16 + l15) * C4_;
            const bf16x8 kb0 = *reinterpret_cast<const bf16x8*>(krow + quad * 8);
            const bf16x8 kb1 = *reinterpret_cast<const bf16x8*>(krow + 32 + quad * 8);
            f32x4 z = {0.f, 0.f, 0.f, 0.f};
            z = __builtin_amdgcn_mfma_f32_16x16x32_bf16(a0, kb0, z, 0, 0, 0);
            const f32x4 e = __builtin_amdgcn_mfma_f32_16x16x32_bf16(a1, kb1, z, 0, 0, 0);
            const float civ = sh.a.ci[m0 + s * 16 + l15];
#pragma unroll
            for (int r = 0; r < 4; ++r) {
                const float p = __expf(e[r]) * rli[r] * civ;
                sh.a.p[wave][quad * 4 + r][s * 16 + l15] = bf16_rne(p);
            }
        }
        // same-wave LDS round-trip: in-order DS + compiler lgkmcnt, no barrier
        const bf16x8 pa0 = *reinterpret_cast<const bf16x8*>(&sh.a.p[wave][l15][quad * 8]);
        const bf16x8 pa1 = *reinterpret_cast<const bf16x8*>(&sh.a.p[wave][l15][32 + quad * 8]);
#pragma unroll
        for (int ct = 0; ct < 16; ++ct) {
            const unsigned short* vrow = vb + (size_t)(ct * 16 + l15) * N_ + m0;
            const bf16x8 vb0 = *reinterpret_cast<const bf16x8*>(vrow + quad * 8);
            const bf16x8 vb1 = *reinterpret_cast<const bf16x8*>(vrow + 32 + quad * 8);
            acc[ct] = __builtin_amdgcn_mfma_f32_16x16x32_bf16(pa0, vb0, acc[ct], 0, 0, 0);
            acc[ct] = __builtin_amdgcn_mfma_f32_16x16x32_bf16(pa1, vb1, acc[ct], 0, 0, 0);
        }
    }
    __syncthreads();
    // tree-merge: (1->0, 3->2) then (2->0), chunked by 8 ct to fit red.
#pragma unroll
    for (int chunk = 0; chunk < 2; ++chunk) {
        if (grp == 1 || grp == 3) {
#pragma unroll
            for (int j = 0; j < 8; ++j) {
                const int ct = chunk * 8 + j;
#pragma unroll
                for (int r = 0; r < 4; ++r)
                    sh.red[grp >> 1][ws][j][quad * 4 + r][l15] = acc[ct][r];
            }
        }
        __syncthreads();
        if (grp == 0 || grp == 2) {
#pragma unroll
            for (int j = 0; j < 8; ++j) {
                const int ct = chunk * 8 + j;
#pragma unroll
                for (int r = 0; r < 4; ++r)
                    acc[ct][r] += sh.red[grp >> 1][ws][j][quad * 4 + r][l15];
            }
        }
        __syncthreads();
    }
#pragma unroll
    for (int chunk = 0; chunk < 2; ++chunk) {
        if (grp == 2) {
#pragma unroll
            for (int j = 0; j < 8; ++j) {
                const int ct = chunk * 8 + j;
#pragma unroll
                for (int r = 0; r < 4; ++r)
                    sh.red[0][ws][j][quad * 4 + r][l15] = acc[ct][r];
            }
        }
        __syncthreads();
        if (grp == 0) {
#pragma unroll
            for (int j = 0; j < 8; ++j) {
                const int ct = chunk * 8 + j;
#pragma unroll
                for (int r = 0; r < 4; ++r)
                    acc[ct][r] += sh.red[0][ws][j][quad * 4 + r][l15];
            }
        }
        __syncthreads();
    }
    if (grp == 0) {
#pragma unroll
        for (int ct = 0; ct < 16; ++ct) {
            const int c = ct * 16 + l15;
            const float4 xv = *reinterpret_cast<const float4*>(
                &x[((size_t)b * C_ + c) * N_ + n0 + quad * 4]);
            const float xvr[4] = {xv.x, xv.y, xv.z, xv.w};
#pragma unroll
            for (int r = 0; r < 4; ++r)
                dsm[ws * 16 + quad * 4 + r][c] = bf16_rne(xvr[r] - acc[ct][r]);
        }
    }
    __syncthreads();
    // wt GEMM: 4 strips x 4 o-quarters across the 16 waves
    bf16x8 da[8];
#pragma unroll
    for (int k = 0; k < 8; ++k)
        da[k] = *reinterpret_cast<const bf16x8*>(&dsm[ws * 16 + l15][k * 32 + quad * 8]);
    f32x4 tacc[4];
#pragma unroll
    for (int j = 0; j < 4; ++j) tacc[j] = (f32x4){0.f, 0.f, 0.f, 0.f};
#pragma unroll
    for (int j = 0; j < 4; ++j) {
        const int ot = grp * 4 + j;
#pragma unroll
        for (int k = 0; k < 8; ++k) {
            const bf16x8 wb = *reinterpret_cast<const bf16x8*>(
                wtb + (size_t)(ot * 16 + l15) * C_ + k * 32 + quad * 8);
            tacc[j] = __builtin_amdgcn_mfma_f32_16x16x32_bf16(da[k], wb, tacc[j], 0, 0, 0);
        }
    }
#pragma unroll
    for (int j = 0; j < 4; ++j) {
        const int o = (grp * 4 + j) * 16 + l15;
        const float g = gamma[o] * rsqrtf(rvar[o] + 1e-5f);
        const float mn = rmean[o], bbet = beta[o], bo = bt[o];
        const size_t oi = ((size_t)b * C_ + o) * N_ + n0 + quad * 4;
        const float4 xo = *reinterpret_cast<const float4*>(&x[oi]);
        float4 res;
        res.x = xo.x + fmaxf((tacc[j][0] + bo - mn) * g + bbet, 0.f);
        res.y = xo.y + fmaxf((tacc[j][1] + bo - mn) * g + bbet, 0.f);
        res.z = xo.z + fmaxf((tacc[j][2] + bo - mn) * g + bbet, 0.f);
        res.w = xo.w + fmaxf((tacc[j][3] + bo - mn) * g + bbet, 0.f);
        *reinterpret_cast<float4*>(&out[oi]) = res;
    }
}

}  // namespace

extern "C" void kernel_launch(void* const* d_in, const int* in_sizes, int n_in,
                              void* d_out, int out_size, void* d_ws, size_t ws_size,
                              hipStream_t stream) {
    const float* x = (const float*)d_in[0];
    const float* wq = (const float*)d_in[1];
    const float* wv = (const float*)d_in[2];
    const float* bv = (const float*)d_in[3];
    const float* wt = (const float*)d_in[4];
    const float* bt = (const float*)d_in[5];
    const float* gamma = (const float*)d_in[6];
    const float* beta = (const float*)d_in[7];
    const float* rmean = (const float*)d_in[8];
    const float* rvar = (const float*)d_in[9];
    float* out = (float*)d_out;

    char* base = (char*)d_ws;
    unsigned short* qkT = (unsigned short*)base;                        // 2 MB
    unsigned short* vw = (unsigned short*)(base + (2u << 20));          // 8 MB
    unsigned short* wtb = (unsigned short*)(base + (10u << 20));        // 128 KB
    unsigned short* wcomb = (unsigned short*)(base + (10u << 20) + (128u << 10));
    float* rowsuminv = (float*)(base + (10u << 20) + (288u << 10));     // 64 KB
    float* colsuminv = (float*)(base + (10u << 20) + (352u << 10));     // 64 KB

    cvt_kernel<<<dim3(144), dim3(256), 0, stream>>>(wq, wv, wt, wcomb, wtb);
    proj_kernel<<<dim3(N_ / 64, 4, B_), dim3(256), 0, stream>>>(x, wcomb, bv, qkT, vw);
    rowsum_kernel<<<dim3(N_ / 64, B_), dim3(1024), 0, stream>>>(qkT, rowsuminv);
    colsum_kernel<<<dim3(N_ / 64, B_), dim3(1024), 0, stream>>>(qkT, rowsuminv, colsuminv);
    final_kernel<<<dim3(N_ / 64, B_), dim3(1024), 0, stream>>>(
        x, qkT, vw, wtb, rowsuminv, colsuminv, bt, gamma, beta, rmean, rvar, out);
}

// Round 6
// 478.308 us; speedup vs baseline: 20.7836x; 1.0317x over previous
//
#include <hip/hip_runtime.h>
#include <math.h>

namespace {

constexpr int B_ = 4;
constexpr int C_ = 256;
constexpr int C4_ = 64;
constexpr int N_ = 4096;

typedef __attribute__((ext_vector_type(8))) short bf16x8;
typedef __attribute__((ext_vector_type(4))) float f32x4;

__device__ __forceinline__ unsigned short bf16_rne(float f) {
    unsigned u = __float_as_uint(f);
    u += 0x7fffu + ((u >> 16) & 1u);
    return (unsigned short)(u >> 16);
}

// Convert wq||wv -> wcomb bf16 [320,256], wt -> wtb bf16 [256,256].
__global__ __launch_bounds__(256) void cvt_kernel(
        const float* __restrict__ wq, const float* __restrict__ wv,
        const float* __restrict__ wt, unsigned short* __restrict__ wcomb,
        unsigned short* __restrict__ wtb) {
    const int i = (blockIdx.x * 256 + threadIdx.x) * 4;
    const float* src;
    unsigned short* dst;
    if (i < 16384) { src = wq + i; dst = wcomb + i; }
    else if (i < 81920) { src = wv + (i - 16384); dst = wcomb + i; }
    else { src = wt + (i - 81920); dst = wtb + (i - 81920); }
    const float4 f = *reinterpret_cast<const float4*>(src);
    ushort4 u;
    u.x = bf16_rne(f.x); u.y = bf16_rne(f.y);
    u.z = bf16_rne(f.z); u.w = bf16_rne(f.w);
    *reinterpret_cast<ushort4*>(dst) = u;
}

// MFMA projection: one 1024-thread block per 64-n tile; 16 waves = 4 n-strips
// x 4 o-quarters (5 ot each). x staged once per block.
__global__ __launch_bounds__(1024, 4) void proj_kernel(
        const float* __restrict__ x, const unsigned short* __restrict__ wcomb,
        const float* __restrict__ bv, unsigned short* __restrict__ qkT,
        unsigned short* __restrict__ v) {
    __shared__ unsigned short xs[2][64][40];
    const int b = blockIdx.y;
    const int n0 = blockIdx.x * 64;
    const int tid = threadIdx.x;
    const int wave = tid >> 6, lane = tid & 63;
    const int ws = wave & 3, oq = wave >> 2;
    const int quad = lane >> 4, l15 = lane & 15;
    const int ca = tid >> 6, na = tid & 63;
    const int cb = (tid + 1024) >> 6, nb2 = (tid + 1024) & 63;
    f32x4 acc[5];
#pragma unroll
    for (int ot = 0; ot < 5; ++ot) acc[ot] = (f32x4){0.f, 0.f, 0.f, 0.f};
    xs[0][na][ca] = bf16_rne(x[((size_t)b * C_ + ca) * N_ + n0 + na]);
    xs[0][nb2][cb] = bf16_rne(x[((size_t)b * C_ + cb) * N_ + n0 + nb2]);
    __syncthreads();
    for (int ch = 0; ch < 8; ++ch) {
        const int buf = ch & 1;
        float la = 0.f, lb = 0.f;
        if (ch < 7) {
            la = x[((size_t)b * C_ + (ch + 1) * 32 + ca) * N_ + n0 + na];
            lb = x[((size_t)b * C_ + (ch + 1) * 32 + cb) * N_ + n0 + nb2];
        }
        const bf16x8 a = *reinterpret_cast<const bf16x8*>(&xs[buf][ws * 16 + l15][quad * 8]);
#pragma unroll
        for (int ot = 0; ot < 5; ++ot) {
            const int gro = oq * 5 + ot;
            const bf16x8 wb = *reinterpret_cast<const bf16x8*>(
                wcomb + (size_t)(gro * 16 + l15) * C_ + ch * 32 + quad * 8);
            acc[ot] = __builtin_amdgcn_mfma_f32_16x16x32_bf16(a, wb, acc[ot], 0, 0, 0);
        }
        if (ch < 7) {
            xs[buf ^ 1][na][ca] = bf16_rne(la);
            xs[buf ^ 1][nb2][cb] = bf16_rne(lb);
        }
        __syncthreads();
    }
    const int n = n0 + ws * 16 + quad * 4;
#pragma unroll
    for (int ot = 0; ot < 5; ++ot) {
        const int gro = oq * 5 + ot;
        if (gro < 4) {
            const int o = gro * 16 + l15;
#pragma unroll
            for (int r = 0; r < 4; ++r)
                qkT[((size_t)b * N_ + n + r) * C4_ + o] = bf16_rne(acc[ot][r]);
        } else {
            const int c = (gro - 4) * 16 + l15;
            const float bb = bv[c];
            ushort4 u;
            u.x = bf16_rne(acc[ot][0] + bb);
            u.y = bf16_rne(acc[ot][1] + bb);
            u.z = bf16_rne(acc[ot][2] + bb);
            u.w = bf16_rne(acc[ot][3] + bb);
            *reinterpret_cast<ushort4*>(&v[((size_t)b * C_ + c) * N_ + n]) = u;
        }
    }
}

// rowsuminv[b,n] = 1/sum_m exp(e[n,m]). 16 waves = 4 n-strips x 4 m-subtiles,
// all walking the same m-tile staged into LDS (dbuf) with coalesced loads.
__global__ __launch_bounds__(1024, 4) void rowsum_kernel(
        const unsigned short* __restrict__ qkT, float* __restrict__ rowsuminv) {
    __shared__ unsigned short kt[2][64][68];
    __shared__ float red[4][4][16];
    const int b = blockIdx.y;
    const int tid = threadIdx.x;
    const int wave = tid >> 6, lane = tid & 63;
    const int ws = wave & 3, sg = wave >> 2;
    const int quad = lane >> 4, l15 = lane & 15;
    const int n0 = blockIdx.x * 64;
    const unsigned short* qb = qkT + (size_t)b * N_ * C4_;
    const unsigned short* qrow = qb + (size_t)(n0 + ws * 16 + l15) * C4_;
    const bf16x8 a0 = *reinterpret_cast<const bf16x8*>(qrow + quad * 8);
    const bf16x8 a1 = *reinterpret_cast<const bf16x8*>(qrow + 32 + quad * 8);
    const int srow = tid >> 3, soff = tid & 7;
    if (tid < 512) {
        const bf16x8 sk = *reinterpret_cast<const bf16x8*>(qb + (size_t)srow * C4_ + soff * 8);
        *reinterpret_cast<bf16x8*>(&kt[0][srow][soff * 8]) = sk;
    }
    __syncthreads();
    float cs[4] = {};
    for (int mt = 0; mt < 64; ++mt) {
        const int buf = mt & 1;
        bf16x8 nk;
        if (mt < 63 && tid < 512)
            nk = *reinterpret_cast<const bf16x8*>(
                qb + (size_t)((mt + 1) * 64 + srow) * C4_ + soff * 8);
        const bf16x8 kb0 = *reinterpret_cast<const bf16x8*>(&kt[buf][sg * 16 + l15][quad * 8]);
        const bf16x8 kb1 = *reinterpret_cast<const bf16x8*>(&kt[buf][sg * 16 + l15][32 + quad * 8]);
        f32x4 z = {0.f, 0.f, 0.f, 0.f};
        z = __builtin_amdgcn_mfma_f32_16x16x32_bf16(a0, kb0, z, 0, 0, 0);
        const f32x4 e = __builtin_amdgcn_mfma_f32_16x16x32_bf16(a1, kb1, z, 0, 0, 0);
#pragma unroll
        for (int r = 0; r < 4; ++r) cs[r] += __expf(e[r]);
        if (mt < 63 && tid < 512)
            *reinterpret_cast<bf16x8*>(&kt[buf ^ 1][srow][soff * 8]) = nk;
        __syncthreads();
    }
#pragma unroll
    for (int r = 0; r < 4; ++r) {
#pragma unroll
        for (int k = 1; k <= 8; k <<= 1) cs[r] += __shfl_xor(cs[r], k, 64);
        if (l15 == 0) red[sg][ws][quad * 4 + r] = cs[r];
    }
    __syncthreads();
    if (tid < 64) {
        const int ws2 = tid >> 4, row = tid & 15;
        const float sum = red[0][ws2][row] + red[1][ws2][row] +
                          red[2][ws2][row] + red[3][ws2][row];
        rowsuminv[(size_t)b * N_ + n0 + ws2 * 16 + row] = 1.0f / sum;
    }
}

// colsuminv[b,m] = 1/(1e-9 + sum_n exp(e[n,m])*rowsuminv[n]).
// 16 waves = 4 m-strips (kb in regs) x 4 n-subtiles of the staged q-tile.
__global__ __launch_bounds__(1024, 4) void colsum_kernel(
        const unsigned short* __restrict__ qkT, const float* __restrict__ rowsuminv,
        float* __restrict__ colsuminv) {
    __shared__ float rl[N_];
    __shared__ unsigned short qt[2][64][68];
    __shared__ float red[4][4][16];
    const int b = blockIdx.y;
    const int tid = threadIdx.x;
    const int wave = tid >> 6, lane = tid & 63;
    const int mw = wave & 3, ng = wave >> 2;
    const int quad = lane >> 4, l15 = lane & 15;
    const int m0 = blockIdx.x * 64;
    for (int i = tid; i < N_; i += 1024) rl[i] = rowsuminv[(size_t)b * N_ + i];
    const unsigned short* qb = qkT + (size_t)b * N_ * C4_;
    const unsigned short* krow = qb + (size_t)(m0 + mw * 16 + l15) * C4_;
    const bf16x8 kb0 = *reinterpret_cast<const bf16x8*>(krow + quad * 8);
    const bf16x8 kb1 = *reinterpret_cast<const bf16x8*>(krow + 32 + quad * 8);
    const int srow = tid >> 3, soff = tid & 7;
    if (tid < 512) {
        const bf16x8 sq = *reinterpret_cast<const bf16x8*>(qb + (size_t)srow * C4_ + soff * 8);
        *reinterpret_cast<bf16x8*>(&qt[0][srow][soff * 8]) = sq;
    }
    __syncthreads();
    float cs = 0.f;
    for (int nt = 0; nt < 64; ++nt) {
        const int buf = nt & 1;
        bf16x8 nq;
        if (nt < 63 && tid < 512)
            nq = *reinterpret_cast<const bf16x8*>(
                qb + (size_t)((nt + 1) * 64 + srow) * C4_ + soff * 8);
        const bf16x8 a0 = *reinterpret_cast<const bf16x8*>(&qt[buf][ng * 16 + l15][quad * 8]);
        const bf16x8 a1 = *reinterpret_cast<const bf16x8*>(&qt[buf][ng * 16 + l15][32 + quad * 8]);
        f32x4 z = {0.f, 0.f, 0.f, 0.f};
        z = __builtin_amdgcn_mfma_f32_16x16x32_bf16(a0, kb0, z, 0, 0, 0);
        const f32x4 e = __builtin_amdgcn_mfma_f32_16x16x32_bf16(a1, kb1, z, 0, 0, 0);
        const int nb = nt * 64 + ng * 16 + quad * 4;
#pragma unroll
        for (int r = 0; r < 4; ++r) cs += __expf(e[r]) * rl[nb + r];
        if (nt < 63 && tid < 512)
            *reinterpret_cast<bf16x8*>(&qt[buf ^ 1][srow][soff * 8]) = nq;
        __syncthreads();
    }
    cs += __shfl_xor(cs, 16, 64);
    cs += __shfl_xor(cs, 32, 64);
    if (quad == 0) red[ng][mw][l15] = cs;
    __syncthreads();
    if (tid < 64) {
        const int mw2 = tid >> 4, l = tid & 15;
        const float sum = red[0][mw2][l] + red[1][mw2][l] +
                          red[2][mw2][l] + red[3][mw2][l];
        colsuminv[(size_t)b * N_ + m0 + mw2 * 16 + l] = 1.0f / (1e-9f + sum);
    }
}

// Final: 16 waves = 4 n-strips x 4 ct-quarters, all on the same m-tile.
// v-tile (32 KB) + k-tile (8 KB) staged into dbuf LDS; energy computed once
// per (strip, m-subtile); p shared via LDS; PV + wt GEMM via MFMA.
__global__ __launch_bounds__(1024, 4) void final_kernel(
        const float* __restrict__ x, const unsigned short* __restrict__ qkT,
        const unsigned short* __restrict__ v, const unsigned short* __restrict__ wtb,
        const float* __restrict__ rowsuminv, const float* __restrict__ colsuminv,
        const float* __restrict__ bt, const float* __restrict__ gamma,
        const float* __restrict__ beta, const float* __restrict__ rmean,
        const float* __restrict__ rvar, float* __restrict__ out) {
    __shared__ float ci[N_];                                              // 16 KB
    __shared__ union {
        unsigned short vt[2][256][68];                                    // 68 KB
        unsigned short dsm[64][268];                                      // 33.5 KB
    } u;
    __shared__ unsigned short p[4][16][68];                               // 8.5 KB
    __shared__ unsigned short kt[2][64][68];                              // 17 KB
    const int b = blockIdx.y;
    const int tid = threadIdx.x;
    const int wave = tid >> 6, lane = tid & 63;
    const int ws = wave & 3, grp = wave >> 2;
    const int quad = lane >> 4, l15 = lane & 15;
    const int n0 = blockIdx.x * 64;
    for (int i = tid; i < N_; i += 1024) ci[i] = colsuminv[(size_t)b * N_ + i];
    const unsigned short* qb = qkT + (size_t)b * N_ * C4_;
    const unsigned short* qrow = qb + (size_t)(n0 + ws * 16 + l15) * C4_;
    const bf16x8 a0 = *reinterpret_cast<const bf16x8*>(qrow + quad * 8);
    const bf16x8 a1 = *reinterpret_cast<const bf16x8*>(qrow + 32 + quad * 8);
    float rli[4];
#pragma unroll
    for (int r = 0; r < 4; ++r)
        rli[r] = rowsuminv[(size_t)b * N_ + n0 + ws * 16 + quad * 4 + r];
    const unsigned short* vbg = v + (size_t)b * C_ * N_;
    const int vrow = tid >> 3, voff = tid & 7;
    // prologue: stage tile 0
    {
        const bf16x8 sv0 = *reinterpret_cast<const bf16x8*>(vbg + (size_t)vrow * N_ + voff * 8);
        const bf16x8 sv1 = *reinterpret_cast<const bf16x8*>(vbg + (size_t)(vrow + 128) * N_ + voff * 8);
        *reinterpret_cast<bf16x8*>(&u.vt[0][vrow][voff * 8]) = sv0;
        *reinterpret_cast<bf16x8*>(&u.vt[0][vrow + 128][voff * 8]) = sv1;
        if (tid < 512) {
            const bf16x8 sk = *reinterpret_cast<const bf16x8*>(qb + (size_t)vrow * C4_ + voff * 8);
            *reinterpret_cast<bf16x8*>(&kt[0][vrow][voff * 8]) = sk;
        }
    }
    __syncthreads();
    f32x4 acc[4];
#pragma unroll
    for (int j = 0; j < 4; ++j) acc[j] = (f32x4){0.f, 0.f, 0.f, 0.f};
    for (int mt = 0; mt < 64; ++mt) {
        const int buf = mt & 1;
        const int m0 = mt * 64;
        bf16x8 nv0, nv1, nk;
        if (mt < 63) {
            nv0 = *reinterpret_cast<const bf16x8*>(vbg + (size_t)vrow * N_ + m0 + 64 + voff * 8);
            nv1 = *reinterpret_cast<const bf16x8*>(vbg + (size_t)(vrow + 128) * N_ + m0 + 64 + voff * 8);
            if (tid < 512)
                nk = *reinterpret_cast<const bf16x8*>(
                    qb + (size_t)(m0 + 64 + vrow) * C4_ + voff * 8);
        }
        // energy for (ws strip, grp m-subtile) from staged k-tile
        const bf16x8 kb0 = *reinterpret_cast<const bf16x8*>(&kt[buf][grp * 16 + l15][quad * 8]);
        const bf16x8 kb1 = *reinterpret_cast<const bf16x8*>(&kt[buf][grp * 16 + l15][32 + quad * 8]);
        f32x4 z = {0.f, 0.f, 0.f, 0.f};
        z = __builtin_amdgcn_mfma_f32_16x16x32_bf16(a0, kb0, z, 0, 0, 0);
        const f32x4 e = __builtin_amdgcn_mfma_f32_16x16x32_bf16(a1, kb1, z, 0, 0, 0);
        const float civ = ci[m0 + grp * 16 + l15];
#pragma unroll
        for (int r = 0; r < 4; ++r)
            p[ws][quad * 4 + r][grp * 16 + l15] = bf16_rne(__expf(e[r]) * rli[r] * civ);
        __syncthreads();  // B1: p ready; all energy reads of kt[buf] done
        if (mt < 63) {
            *reinterpret_cast<bf16x8*>(&u.vt[buf ^ 1][vrow][voff * 8]) = nv0;
            *reinterpret_cast<bf16x8*>(&u.vt[buf ^ 1][vrow + 128][voff * 8]) = nv1;
            if (tid < 512)
                *reinterpret_cast<bf16x8*>(&kt[buf ^ 1][vrow][voff * 8]) = nk;
        }
        const bf16x8 pa0 = *reinterpret_cast<const bf16x8*>(&p[ws][l15][quad * 8]);
        const bf16x8 pa1 = *reinterpret_cast<const bf16x8*>(&p[ws][l15][32 + quad * 8]);
#pragma unroll
        for (int j = 0; j < 4; ++j) {
            const int c0 = (grp * 4 + j) * 16;
            const bf16x8 vb0 = *reinterpret_cast<const bf16x8*>(&u.vt[buf][c0 + l15][quad * 8]);
            const bf16x8 vb1 = *reinterpret_cast<const bf16x8*>(&u.vt[buf][c0 + l15][32 + quad * 8]);
            acc[j] = __builtin_amdgcn_mfma_f32_16x16x32_bf16(pa0, vb0, acc[j], 0, 0, 0);
            acc[j] = __builtin_amdgcn_mfma_f32_16x16x32_bf16(pa1, vb1, acc[j], 0, 0, 0);
        }
        __syncthreads();  // B2: PV reads of p/vt[buf] done before next rewrite
    }
    // dsm = x - x_r (bf16); each wave writes its (strip, channel-quarter)
#pragma unroll
    for (int j = 0; j < 4; ++j) {
        const int c = (grp * 4 + j) * 16 + l15;
        const float4 xv = *reinterpret_cast<const float4*>(
            &x[((size_t)b * C_ + c) * N_ + n0 + ws * 16 + quad * 4]);
        const float xvr[4] = {xv.x, xv.y, xv.z, xv.w};
#pragma unroll
        for (int r = 0; r < 4; ++r)
            u.dsm[ws * 16 + quad * 4 + r][c] = bf16_rne(xvr[r] - acc[j][r]);
    }
    __syncthreads();
    // wt GEMM: 4 strips x 4 o-quarters
    bf16x8 da[8];
#pragma unroll
    for (int k = 0; k < 8; ++k)
        da[k] = *reinterpret_cast<const bf16x8*>(&u.dsm[ws * 16 + l15][k * 32 + quad * 8]);
    f32x4 tacc[4];
#pragma unroll
    for (int j = 0; j < 4; ++j) tacc[j] = (f32x4){0.f, 0.f, 0.f, 0.f};
#pragma unroll
    for (int j = 0; j < 4; ++j) {
        const int ot = grp * 4 + j;
#pragma unroll
        for (int k = 0; k < 8; ++k) {
            const bf16x8 wb = *reinterpret_cast<const bf16x8*>(
                wtb + (size_t)(ot * 16 + l15) * C_ + k * 32 + quad * 8);
            tacc[j] = __builtin_amdgcn_mfma_f32_16x16x32_bf16(da[k], wb, tacc[j], 0, 0, 0);
        }
    }
#pragma unroll
    for (int j = 0; j < 4; ++j) {
        const int o = (grp * 4 + j) * 16 + l15;
        const float g = gamma[o] * rsqrtf(rvar[o] + 1e-5f);
        const float mn = rmean[o], bbet = beta[o], bo = bt[o];
        const size_t oi = ((size_t)b * C_ + o) * N_ + n0 + ws * 16 + quad * 4;
        const float4 xo = *reinterpret_cast<const float4*>(&x[oi]);
        float4 res;
        res.x = xo.x + fmaxf((tacc[j][0] + bo - mn) * g + bbet, 0.f);
        res.y = xo.y + fmaxf((tacc[j][1] + bo - mn) * g + bbet, 0.f);
        res.z = xo.z + fmaxf((tacc[j][2] + bo - mn) * g + bbet, 0.f);
        res.w = xo.w + fmaxf((tacc[j][3] + bo - mn) * g + bbet, 0.f);
        *reinterpret_cast<float4*>(&out[oi]) = res;
    }
}

}  // namespace

extern "C" void kernel_launch(void* const* d_in, const int* in_sizes, int n_in,
                              void* d_out, int out_size, void* d_ws, size_t ws_size,
                              hipStream_t stream) {
    const float* x = (const float*)d_in[0];
    const float* wq = (const float*)d_in[1];
    const float* wv = (const float*)d_in[2];
    const float* bv = (const float*)d_in[3];
    const float* wt = (const float*)d_in[4];
    const float* bt = (const float*)d_in[5];
    const float* gamma = (const float*)d_in[6];
    const float* beta = (const float*)d_in[7];
    const float* rmean = (const float*)d_in[8];
    const float* rvar = (const float*)d_in[9];
    float* out = (float*)d_out;

    char* base = (char*)d_ws;
    unsigned short* qkT = (unsigned short*)base;                        // 2 MB
    unsigned short* vw = (unsigned short*)(base + (2u << 20));          // 8 MB
    unsigned short* wtb = (unsigned short*)(base + (10u << 20));        // 128 KB
    unsigned short* wcomb = (unsigned short*)(base + (10u << 20) + (128u << 10));
    float* rowsuminv = (float*)(base + (10u << 20) + (288u << 10));     // 64 KB
    float* colsuminv = (float*)(base + (10u << 20) + (352u << 10));     // 64 KB

    cvt_kernel<<<dim3(144), dim3(256), 0, stream>>>(wq, wv, wt, wcomb, wtb);
    proj_kernel<<<dim3(N_ / 64, B_), dim3(1024), 0, stream>>>(x, wcomb, bv, qkT, vw);
    rowsum_kernel<<<dim3(N_ / 64, B_), dim3(1024), 0, stream>>>(qkT, rowsuminv);
    colsum_kernel<<<dim3(N_ / 64, B_), dim3(1024), 0, stream>>>(qkT, rowsuminv, colsuminv);
    final_kernel<<<dim3(N_ / 64, B_), dim3(1024), 0, stream>>>(
        x, qkT, vw, wtb, rowsuminv, colsuminv, bt, gamma, beta, rmean, rvar, out);
}